// Round 11
// baseline (572.286 us; speedup 1.0000x reference)
//
#include <hip/hip_runtime.h>
#include <hip/hip_bf16.h>

#define NEG_SLOPE 0.01f
#define CHH 4096           // edges per block in hist (LDS-aggregated)
#define CH 12288           // edges per block in scatter (3x: 84B->251B runs)
#define SB 512             // scatter2 block size (8 waves in 1 block = same
                           // waves/CU as the old 2x256 config -> occupancy kept)
#define PAD 16             // 64B stride for contended global counters
// Dual bucket sort: row-bucketed CSR for the gather, col-bucketed staging for
// the presum (cw) aggregation -> NO per-edge global atomics anywhere.
// bucket id = id >> 8 (256 ids per bucket); NB = ceil(N/256) <= 512.
// Packing: {other_id (<2^24) | low8(key_id) << 24}.
// scatter2: in-block LDS counting sort so staging writes stream out as
// contiguous runs per bucket (evidence R3->R4: fixed 4x write amplification).
// R10 evidence: runs of CH/NB edges; at CH=4096 runs are 84B -> 1.75x line
// amplification (WRITE 81MB vs 51 logical). CH=12288 -> 251B runs -> 1.27x.
// rowfin: fused rowdeg+rowsort. Whole bucket's sorted permutation is staged in
// LDS (pass1 hist+deg, pass2 place into 72KB ebuf, pass3 linear stream-out),
// so ALL reads of the bucket range finish before ANY write -> sorted overlays
// stagingR IN-PLACE (block-exclusive range).
// Bucket size ~ Binomial(3.2M, 256/1e5): mean 8192, sigma 90; CAP=9216=+11sig.
// ORDERING: rowfin -> col_finalize (stagingC+dinv) -> h1 (regB over stagingC)
//           -> gather (sorted regA, h1b regB) -> h2pool.
// h2+sum2 fused (h2pool): h2 never materialized (saves 52MB roundtrip).
// R8 LESSON (do not retry): block-per-bucket LDS-accumulating GATHER collapsed
// parallelism (391 blocks, 64 random loads in flight) -> 679us. Random-gather
// needs ~400K independent threads. rowfin/scatter2 only STREAM linearly.
#define NT 32              // col tiles (col < 2^17 -> tile = col>>12 in [0,32))
#define TILE_SHIFT 12      // 256KB h1b tiles -> gather window L2-resident
#define KEYS (256 * NT)    // row-sort bins: (rowlow, tile)
#define CAP 9216           // rowfin LDS staging capacity (entries per bucket)

__device__ __forceinline__ void atomAddF(float* p, float v) {
    unsafeAtomicAdd(p, v);
}

// bf16 pack/unpack (round-to-nearest-even; finite values only)
__device__ __forceinline__ unsigned bf16rn(float f) {
    unsigned u = __float_as_uint(f);
    return (u + 0x7FFFu + ((u >> 16) & 1u)) >> 16;
}
__device__ __forceinline__ unsigned pack2(float a, float b) {
    return bf16rn(a) | (bf16rn(b) << 16);
}
__device__ __forceinline__ float blo(unsigned u) { return __uint_as_float(u << 16); }
__device__ __forceinline__ float bhi(unsigned u) { return __uint_as_float(u & 0xFFFF0000u); }

// wave-inclusive scan of v (64 lanes)
__device__ __forceinline__ int waveInclScan(int v, int lane) {
#pragma unroll
    for (int off = 1; off < 64; off <<= 1) {
        int u = __shfl_up(v, off);
        if (lane >= off) v += u;
    }
    return v;
}

// ---- phase 1: dual bucket histogram (row and col), block-aggregated -----
__global__ void hist2_kernel(const int* __restrict__ row, const int* __restrict__ col,
                             int* __restrict__ bhR, int* __restrict__ bhC, int E, int NB) {
    __shared__ int lhR[512];
    __shared__ int lhC[512];
    for (int t = threadIdx.x; t < 512; t += 256) { lhR[t] = 0; lhC[t] = 0; }
    __syncthreads();
    int base = blockIdx.x * CHH;
    int end = min(base + CHH, E);
    for (int e = base + threadIdx.x; e < end; e += 256) {
        atomicAdd(&lhR[row[e] >> 8], 1);
        atomicAdd(&lhC[col[e] >> 8], 1);
    }
    __syncthreads();
    for (int t = threadIdx.x; t < NB; t += 256) {
        if (lhR[t]) atomicAdd(&bhR[t * PAD], lhR[t]);
        if (lhC[t]) atomicAdd(&bhC[t * PAD], lhC[t]);
    }
}

// ---- phase 2: exclusive scan of bucket counts (NB <= 512), init cursors -
__global__ void bucket_scan_kernel(const int* __restrict__ bhist_p, int* __restrict__ bbase,
                                   int* __restrict__ bcursor_p, int* __restrict__ rowptr,
                                   int NB, int N, int E) {
    __shared__ int s[512];
    int t = threadIdx.x;
    int v = (t < NB) ? bhist_p[t * PAD] : 0;
    s[t] = v;
    __syncthreads();
    for (int off = 1; off < 512; off <<= 1) {
        int x = (t >= off) ? s[t - off] : 0;
        __syncthreads();
        s[t] += x;
        __syncthreads();
    }
    if (t < NB) { bbase[t] = s[t] - v; bcursor_p[t * PAD] = s[t] - v; }
    if (t == 0) { bbase[NB] = E; rowptr[N] = E; }
}

// ---- phase 3: dual scatter with in-block LDS counting sort --------------
// stagingR (row-bucketed): {col | rowlow<<24, attr}
// stagingC (col-bucketed): {row | collow<<24, attr}
// 512 threads, CH=12288 -> per-bucket runs ~31 edges (251B) -> low write amp.
__global__ void __launch_bounds__(SB, 1)
scatter2_kernel(const int* __restrict__ row, const int* __restrict__ col,
                const float* __restrict__ attr,
                int* __restrict__ bcurR, int* __restrict__ bcurC,
                int2* __restrict__ stagingR, int2* __restrict__ stagingC,
                int E, int NB) {
    __shared__ int lh[512];
    __shared__ int lbase[512];
    __shared__ int loff[512];
    __shared__ int lcur[512];
    __shared__ int wsum[8];
    __shared__ int2 buf[CH];              // 96KB: block's edges grouped by bucket
    __shared__ unsigned short bkid[CH];   // 24KB: bucket id per entry
    int t = threadIdx.x;
    int lane = t & 63, wv = t >> 6;
    int base = blockIdx.x * CH;
    int end = min(base + CH, E);
    int cnt = end - base;

    for (int side = 0; side < 2; side++) {
        const int* key   = side ? col : row;
        const int* other = side ? row : col;
        int* bcur        = side ? bcurC : bcurR;
        int2* out        = side ? stagingC : stagingR;
        // hist
        if (t < 512) { lh[t] = 0; lcur[t] = 0; }
        __syncthreads();
        for (int e = base + t; e < end; e += SB)
            atomicAdd(&lh[key[e] >> 8], 1);
        __syncthreads();
        // reserve global runs
        for (int k = t; k < NB; k += SB)
            if (lh[k]) lbase[k] = atomicAdd(&bcur[k * PAD], lh[k]);
        // local exclusive scan of lh[0..511]: one bin per thread, shfl scan
        int v = lh[t];
        int incl = waveInclScan(v, lane);
        if (lane == 63) wsum[wv] = incl;
        __syncthreads();
        int wadd = 0;
        for (int w = 0; w < wv; w++) wadd += wsum[w];
        loff[t] = incl + wadd - v;   // exclusive prefix
        __syncthreads();
        // place into LDS grouped by bucket
        for (int e = base + t; e < end; e += SB) {
            int k = key[e], o = other[e];
            int bk = k >> 8;
            int rank = atomicAdd(&lcur[bk], 1);
            int lpos = loff[bk] + rank;
            buf[lpos] = make_int2(o | ((k & 255) << 24), __float_as_int(attr[e]));
            bkid[lpos] = (unsigned short)bk;
        }
        __syncthreads();
        // coalesced write-out: consecutive j -> consecutive dst within runs
        for (int j = t; j < cnt; j += SB) {
            int bk = bkid[j];
            out[lbase[bk] + (j - loff[bk])] = buf[j];
        }
        __syncthreads();
    }
}

// ---- phase 4a: fused degree + counting sort, IN-PLACE -------------------
// Block b owns bucket b = rows [b*256, b*256+256) exclusively.
// pass1: hist (rowlow, col>>12) + deg sums  (global read 1, linear)
// scan -> cursors; dinv/rowptr written
// pass2: place {col, pre} into LDS ebuf at sorted pos (global read 2, L2-hot)
// pass3: stream ebuf -> sorted (== stagingR region, block-exclusive, linear)
__global__ void __launch_bounds__(256, 1)
rowfin_kernel(const int* __restrict__ bbaseR, const int2* __restrict__ stagingR,
              int2* __restrict__ sorted /*aliases stagingR*/,
              int* __restrict__ rowptr, float* __restrict__ dinv, int N) {
    __shared__ int lcount[KEYS];      // 32KB: counts -> cursors
    __shared__ int2 ebuf[CAP];        // 72KB: sorted bucket staging
    __shared__ float ldeg[256];
    __shared__ float sdinv[256];
    __shared__ int wsum[4];
    int t = threadIdx.x;
    int lane = t & 63, wv = t >> 6;
    int b = blockIdx.x;
    int base = bbaseR[b], end = bbaseR[b + 1];
    int cnt = end - base;
    for (int k = t; k < KEYS; k += 256) lcount[k] = 0;
    ldeg[t] = 0.f;
    __syncthreads();
    // pass1: histogram + degree
    for (int e = base + t; e < end; e += 256) {
        int2 w = stagingR[e];
        int rl = (w.x >> 24) & 255;
        int tile = (w.x & 0xFFFFFF) >> TILE_SHIFT;
        atomicAdd(&lcount[rl * NT + tile], 1);
        atomicAdd(&ldeg[rl], __int_as_float(w.y));
    }
    __syncthreads();
    // per-row serial scan of NT bins; s = row total
    int vals[NT];
    int s = 0;
#pragma unroll
    for (int j = 0; j < NT; j++) { vals[j] = s; s += lcount[t * NT + j]; }
    int incl = waveInclScan(s, lane);
    if (lane == 63) wsum[wv] = incl;
    __syncthreads();
    int wadd = 0;
    for (int w = 0; w < wv; w++) wadd += wsum[w];
    int rowexcl = incl + wadd - s;
#pragma unroll
    for (int j = 0; j < NT; j++) lcount[t * NT + j] = rowexcl + vals[j];  // -> cursors
    int grow = (b << 8) + t;
    float d = ldeg[t];
    float di = d > 0.f ? rsqrtf(d) : 0.f;
    sdinv[t] = di;
    if (grow < N) {
        rowptr[grow] = base + rowexcl;
        dinv[grow] = di;
    }
    __syncthreads();
    // pass2: place into LDS at sorted position (reads L2-hot)
    for (int e = base + t; e < end; e += 256) {
        int2 w = stagingR[e];
        int rl = (w.x >> 24) & 255;
        int c = w.x & 0xFFFFFF;
        int key = rl * NT + (c >> TILE_SHIFT);
        int pos = atomicAdd(&lcount[key], 1);
        float pre = -sdinv[rl] * __int_as_float(w.y);
        int2 v = make_int2(c, __float_as_int(pre));
        if (pos < CAP) ebuf[pos] = v;
        else sorted[base + pos] = v;   // statistically impossible (>mean+11sigma)
    }
    __syncthreads();
    // pass3: linear stream-out over the block's own (fully-read) range
    int lim = min(cnt, CAP);
    for (int j = t; j < lim; j += 256)
        sorted[base + j] = ebuf[j];
}

// ---- phase 4b: per-col-bucket presum (NO global atomics) ----------------
// presum[c] = sum_{e: col=c} -dinv[row_e] * attr_e
// Runs after rowfin (needs dinv); MUST run before h1 (h1 overlays stagingC).
__global__ void col_finalize_kernel(const int* __restrict__ bbaseC,
                                    const int2* __restrict__ stagingC,
                                    const float* __restrict__ dinv,
                                    float* __restrict__ presum, int N) {
    __shared__ float bins[256];
    int t = threadIdx.x;
    int b = blockIdx.x;
    int base = bbaseC[b], end = bbaseC[b + 1];
    bins[t] = 0.f;
    __syncthreads();
    for (int e = base + t; e < end; e += 256) {
        int2 w = stagingC[e];
        int r = w.x & 0xFFFFFF;
        int cl = (w.x >> 24) & 255;
        float pre = -dinv[r] * __int_as_float(w.y);
        atomicAdd(&bins[cl], pre);   // LDS float atomic
    }
    __syncthreads();
    int grow = (b << 8) + t;
    if (grow < N) presum[grow] = bins[t];
}

// ---- h1 = leaky_relu(x @ w1 + b1); also h1b = bf16(dinv[i] * h1) --------
// h1b row = 32 bf16 = 64B = 4 uint4; feature 2k low half, 2k+1 high half.
__global__ void h1_kernel(const float* __restrict__ x, const float* __restrict__ w,
                          const float* __restrict__ b, const float* __restrict__ dinv,
                          float* __restrict__ h1, uint4* __restrict__ h1b, int N) {
    __shared__ float ws[20 * 32];
    __shared__ float bs[32];
    for (int t = threadIdx.x; t < 640; t += blockDim.x) ws[t] = w[t];
    if (threadIdx.x < 32) bs[threadIdx.x] = b[threadIdx.x];
    __syncthreads();
    int i = blockIdx.x * blockDim.x + threadIdx.x;
    if (i >= N) return;
    float xi[20];
#pragma unroll
    for (int k = 0; k < 20; k++) xi[k] = x[i * 20 + k];
    float acc[32];
#pragma unroll
    for (int j = 0; j < 32; j++) acc[j] = bs[j];
#pragma unroll
    for (int k = 0; k < 20; k++) {
        float a = xi[k];
#pragma unroll
        for (int j = 0; j < 32; j++) acc[j] += a * ws[k * 32 + j];
    }
#pragma unroll
    for (int j = 0; j < 32; j++) {
        float v = acc[j];
        acc[j] = v > 0.f ? v : v * NEG_SLOPE;
    }
    float4* h1v = (float4*)(h1 + (long)i * 32);
#pragma unroll
    for (int j4 = 0; j4 < 8; j4++)
        h1v[j4] = make_float4(acc[j4 * 4], acc[j4 * 4 + 1], acc[j4 * 4 + 2], acc[j4 * 4 + 3]);
    float di = dinv[i];
    unsigned u[16];
#pragma unroll
    for (int k = 0; k < 16; k++) u[k] = pack2(di * acc[2 * k], di * acc[2 * k + 1]);
#pragma unroll
    for (int q = 0; q < 4; q++)
        h1b[(long)i * 4 + q] = make_uint4(u[4 * q], u[4 * q + 1], u[4 * q + 2], u[4 * q + 3]);
}

// ---- pure gather-propagate (no atomics) ---------------------------------
// p1[i] = sum_{e in CSR row i} pre_e * h1b[col_e]   (dinv[col] baked into h1b)
// 4 threads per node, each owning 8 bf16 features (one uint4 = 64B/row total).
__global__ void gather_kernel(const int* __restrict__ rowptr, const int2* __restrict__ sorted,
                              const uint4* __restrict__ h1b, uint4* __restrict__ p1b, int N) {
    long idx = (long)blockIdx.x * blockDim.x + threadIdx.x;
    int node = (int)(idx >> 2);
    int part = (int)(idx & 3);
    if (node >= N) return;
    int s0 = rowptr[node], s1 = rowptr[node + 1];
    float acc[8];
#pragma unroll
    for (int k = 0; k < 8; k++) acc[k] = 0.f;
    int e = s0;
    for (; e + 4 <= s1; e += 4) {
        int2 q0 = sorted[e], q1 = sorted[e + 1], q2 = sorted[e + 2], q3 = sorted[e + 3];
        float n0 = __int_as_float(q0.y), n1 = __int_as_float(q1.y);
        float n2 = __int_as_float(q2.y), n3 = __int_as_float(q3.y);
        uint4 v0 = h1b[(long)q0.x * 4 + part];
        uint4 v1 = h1b[(long)q1.x * 4 + part];
        uint4 v2 = h1b[(long)q2.x * 4 + part];
        uint4 v3 = h1b[(long)q3.x * 4 + part];
        acc[0] += n0 * blo(v0.x) + n1 * blo(v1.x) + n2 * blo(v2.x) + n3 * blo(v3.x);
        acc[1] += n0 * bhi(v0.x) + n1 * bhi(v1.x) + n2 * bhi(v2.x) + n3 * bhi(v3.x);
        acc[2] += n0 * blo(v0.y) + n1 * blo(v1.y) + n2 * blo(v2.y) + n3 * blo(v3.y);
        acc[3] += n0 * bhi(v0.y) + n1 * bhi(v1.y) + n2 * bhi(v2.y) + n3 * bhi(v3.y);
        acc[4] += n0 * blo(v0.z) + n1 * blo(v1.z) + n2 * blo(v2.z) + n3 * blo(v3.z);
        acc[5] += n0 * bhi(v0.z) + n1 * bhi(v1.z) + n2 * bhi(v2.z) + n3 * bhi(v3.z);
        acc[6] += n0 * blo(v0.w) + n1 * blo(v1.w) + n2 * blo(v2.w) + n3 * blo(v3.w);
        acc[7] += n0 * bhi(v0.w) + n1 * bhi(v1.w) + n2 * bhi(v2.w) + n3 * bhi(v3.w);
    }
    for (; e < s1; e++) {
        int2 q = sorted[e];
        float nm = __int_as_float(q.y);
        uint4 v = h1b[(long)q.x * 4 + part];
        acc[0] += nm * blo(v.x); acc[1] += nm * bhi(v.x);
        acc[2] += nm * blo(v.y); acc[3] += nm * bhi(v.y);
        acc[4] += nm * blo(v.z); acc[5] += nm * bhi(v.z);
        acc[6] += nm * blo(v.w); acc[7] += nm * bhi(v.w);
    }
    p1b[(long)node * 4 + part] = make_uint4(pack2(acc[0], acc[1]), pack2(acc[2], acc[3]),
                                            pack2(acc[4], acc[5]), pack2(acc[6], acc[7]));
}

// ---- fused h2 + pooled sums (h2 never materialized) ---------------------
// per node: h2 = LRelu(h1 @ w2_0 + p1 @ w2_1 + b2); accumulate
//   sbuf[j]    += h2[j]            and   sbuf[64+j] += cw_i * h2[j]
// via per-feature wave butterfly -> 4 wave partials in LDS -> global atomics.
__global__ void __launch_bounds__(256, 1)
h2pool_kernel(const float* __restrict__ h1, const uint4* __restrict__ p1b,
              const float* __restrict__ presum, const float* __restrict__ dinv,
              const float* __restrict__ w0, const float* __restrict__ w1,
              const float* __restrict__ b, float* __restrict__ sbuf, int N) {
    __shared__ float w0s[32 * 64];
    __shared__ float w1s[32 * 64];
    __shared__ float bs[64];
    __shared__ float wred[4][128];
    for (int t = threadIdx.x; t < 2048; t += blockDim.x) { w0s[t] = w0[t]; w1s[t] = w1[t]; }
    if (threadIdx.x < 64) bs[threadIdx.x] = b[threadIdx.x];
    __syncthreads();
    int i = blockIdx.x * blockDim.x + threadIdx.x;
    int lane = threadIdx.x & 63, wv = threadIdx.x >> 6;
    const float4* w0v = (const float4*)w0s;   // [k*16 + j4]
    const float4* w1v = (const float4*)w1s;
    const float4* bv  = (const float4*)bs;
    float4 acc[16];
    float cwi = 0.f;
    if (i < N) {
#pragma unroll
        for (int j4 = 0; j4 < 16; j4++) acc[j4] = bv[j4];
        const float4* h1v = (const float4*)(h1 + (long)i * 32);
        float pr[32];
#pragma unroll
        for (int q = 0; q < 4; q++) {
            uint4 P = p1b[(long)i * 4 + q];
            pr[8 * q + 0] = blo(P.x); pr[8 * q + 1] = bhi(P.x);
            pr[8 * q + 2] = blo(P.y); pr[8 * q + 3] = bhi(P.y);
            pr[8 * q + 4] = blo(P.z); pr[8 * q + 5] = bhi(P.z);
            pr[8 * q + 6] = blo(P.w); pr[8 * q + 7] = bhi(P.w);
        }
#pragma unroll
        for (int k4 = 0; k4 < 8; k4++) {
            float4 a = h1v[k4];
            float av[4] = {a.x, a.y, a.z, a.w};
#pragma unroll
            for (int s = 0; s < 4; s++) {
                int k = k4 * 4 + s;
                float aa = av[s], pp = pr[k];
#pragma unroll
                for (int j4 = 0; j4 < 16; j4++) {
                    float4 w0r = w0v[k * 16 + j4];
                    float4 w1r = w1v[k * 16 + j4];
                    acc[j4].x += aa * w0r.x + pp * w1r.x;
                    acc[j4].y += aa * w0r.y + pp * w1r.y;
                    acc[j4].z += aa * w0r.z + pp * w1r.z;
                    acc[j4].w += aa * w0r.w + pp * w1r.w;
                }
            }
        }
        // leaky relu
#pragma unroll
        for (int j4 = 0; j4 < 16; j4++) {
            float4 v = acc[j4];
            v.x = v.x > 0.f ? v.x : v.x * NEG_SLOPE;
            v.y = v.y > 0.f ? v.y : v.y * NEG_SLOPE;
            v.z = v.z > 0.f ? v.z : v.z * NEG_SLOPE;
            v.w = v.w > 0.f ? v.w : v.w * NEG_SLOPE;
            acc[j4] = v;
        }
        cwi = presum[i] * dinv[i];
    } else {
#pragma unroll
        for (int j4 = 0; j4 < 16; j4++) acc[j4] = make_float4(0.f, 0.f, 0.f, 0.f);
    }
    // per-feature wave butterfly reduce (plain + cw-weighted)
#pragma unroll
    for (int j4 = 0; j4 < 16; j4++) {
        float4 a = acc[j4];
        float4 c = make_float4(a.x * cwi, a.y * cwi, a.z * cwi, a.w * cwi);
#pragma unroll
        for (int off = 1; off < 64; off <<= 1) {
            a.x += __shfl_xor(a.x, off); a.y += __shfl_xor(a.y, off);
            a.z += __shfl_xor(a.z, off); a.w += __shfl_xor(a.w, off);
            c.x += __shfl_xor(c.x, off); c.y += __shfl_xor(c.y, off);
            c.z += __shfl_xor(c.z, off); c.w += __shfl_xor(c.w, off);
        }
        if (lane == 0) {
            wred[wv][j4 * 4 + 0] = a.x; wred[wv][j4 * 4 + 1] = a.y;
            wred[wv][j4 * 4 + 2] = a.z; wred[wv][j4 * 4 + 3] = a.w;
            wred[wv][64 + j4 * 4 + 0] = c.x; wred[wv][64 + j4 * 4 + 1] = c.y;
            wred[wv][64 + j4 * 4 + 2] = c.z; wred[wv][64 + j4 * 4 + 3] = c.w;
        }
    }
    __syncthreads();
    int t = threadIdx.x;
    if (t < 128) {
        float s = wred[0][t] + wred[1][t] + wred[2][t] + wred[3][t];
        atomAddF(&sbuf[t], s);
    }
}

// ---- pooled = (s1/N)@w30 + (s2/N)@w31 + b3; out = log_softmax -----------
__global__ void final_kernel(const float* __restrict__ sbuf,
                             const float* __restrict__ w30, const float* __restrict__ w31,
                             const float* __restrict__ b3, float* __restrict__ out, float invN) {
    if (threadIdx.x != 0 || blockIdx.x != 0) return;
    const float* s1 = sbuf;
    const float* s2 = sbuf + 64;
    float p[2];
    for (int c = 0; c < 2; c++) {
        float a = 0.f;
        for (int k = 0; k < 64; k++) a += s1[k] * w30[k * 2 + c] + s2[k] * w31[k * 2 + c];
        p[c] = a * invN + b3[c];
    }
    float m = fmaxf(p[0], p[1]);
    float lse = m + logf(expf(p[0] - m) + expf(p[1] - m));
    out[0] = p[0] - lse;
    out[1] = p[1] - lse;
}

extern "C" void kernel_launch(void* const* d_in, const int* in_sizes, int n_in,
                              void* d_out, int out_size, void* d_ws, size_t ws_size,
                              hipStream_t stream) {
    const float* x    = (const float*)d_in[0];
    const int*   ei   = (const int*)d_in[1];
    const float* attr = (const float*)d_in[2];
    const float* w1_0 = (const float*)d_in[3];
    const float* b1   = (const float*)d_in[4];
    const float* w2_0 = (const float*)d_in[5];
    const float* w2_1 = (const float*)d_in[6];
    const float* b2   = (const float*)d_in[7];
    const float* w3_0 = (const float*)d_in[8];
    const float* w3_1 = (const float*)d_in[9];
    const float* b3   = (const float*)d_in[10];

    const int N = in_sizes[0] / 20;   // 100000
    const int E = in_sizes[2];        // 3200000
    const int* row = ei;
    const int* col = ei + E;
    const int NB = (N + 255) >> 8;    // 391 buckets (<= 512)

    // workspace layout (words)
    long big = (long)(2L * E > 64L * N ? 2L * E : 64L * N);
    float* ws = (float*)d_ws;
    float* dinv   = ws;                            // N
    float* presum = ws + N;                        // N
    int*   rowptr = (int*)(ws + 2L * N);           // N+1 (alloc N+4)
    long   off    = 3L * N + 4;
    int*   bhR    = (int*)(ws + off); off += 512L * PAD;   // row hist (padded)
    int*   bhC    = (int*)(ws + off); off += 512L * PAD;   // col hist (padded)
    int*   bbaseR = (int*)(ws + off); off += 516;
    int*   bbaseC = (int*)(ws + off); off += 516;
    int*   bcurR  = (int*)(ws + off); off += 512L * PAD;
    int*   bcurC  = (int*)(ws + off); off += 512L * PAD;
    float* sbuf   = ws + off;         off += 128;
    long   offA   = (off + 15) & ~15L;                     // 64B-align regA
    float* regA   = ws + offA;                  // big: stagingR -> sorted (in-place)
    float* regB   = regA + big;                 // big: stagingC -> h1+p1b+h1b

    int2*  stagingR = (int2*)regA;              // rewritten in-place as sorted
    int2*  sorted   = (int2*)regA;              // == stagingR region; dead after gather
    int2*  stagingC = (int2*)regB;              // dead after col_finalize
    float* h1       = regB;                     // fp32, 32N words (over stagingC)
    uint4* p1b      = (uint4*)(regB + 32L * N); // bf16, 16N words
    uint4* h1b      = (uint4*)(regB + 48L * N); // bf16 (dinv-scaled), 16N words

    // zero accumulated regions (ws is poisoned before every launch)
    hipMemsetAsync(bhR, 0, 2 * 512 * PAD * 4, stream);   // bhR + bhC contiguous
    hipMemsetAsync(sbuf, 0, 128 * 4, stream);

    const int B = 256;
    const int NCHH = (E + CHH - 1) / CHH;   // chunk-blocks for hist
    const int NCH  = (E + CH - 1) / CH;     // chunk-blocks for scatter
    hist2_kernel<<<NCHH, B, 0, stream>>>(row, col, bhR, bhC, E, NB);
    bucket_scan_kernel<<<1, 512, 0, stream>>>(bhR, bbaseR, bcurR, rowptr, NB, N, E);
    bucket_scan_kernel<<<1, 512, 0, stream>>>(bhC, bbaseC, bcurC, rowptr, NB, N, E);
    scatter2_kernel<<<NCH, SB, 0, stream>>>(row, col, attr, bcurR, bcurC, stagingR, stagingC, E, NB);
    rowfin_kernel<<<NB, 256, 0, stream>>>(bbaseR, stagingR, sorted, rowptr, dinv, N);  // in-place
    col_finalize_kernel<<<NB, 256, 0, stream>>>(bbaseC, stagingC, dinv, presum, N);    // frees regB
    h1_kernel<<<(N + B - 1) / B, B, 0, stream>>>(x, w1_0, b1, dinv, h1, h1b, N);
    {
        long t = (long)N * 4;
        gather_kernel<<<(int)((t + B - 1) / B), B, 0, stream>>>(rowptr, sorted, h1b, p1b, N);
    }
    h2pool_kernel<<<(N + B - 1) / B, B, 0, stream>>>(h1, p1b, presum, dinv, w2_0, w2_1, b2, sbuf, N);
    final_kernel<<<1, 64, 0, stream>>>(sbuf, w3_0, w3_1, b3, (float*)d_out, 1.0f / (float)N);
}

// Round 12
// 441.313 us; speedup vs baseline: 1.2968x; 1.2968x over previous
//
#include <hip/hip_runtime.h>
#include <hip/hip_bf16.h>

#define NEG_SLOPE 0.01f
#define CH 4096            // edges per block in hist/scatter (LDS-aggregated)
#define PAD 16             // 64B stride for contended global counters
// Dual bucket sort: row-bucketed CSR for the gather, col-bucketed staging for
// the presum (cw) aggregation -> NO per-edge global atomics anywhere.
// bucket id = id >> 8 (256 ids per bucket); NB = ceil(N/256) <= 512.
// Packing: {other_id (<2^24) | low8(key_id) << 24}.
// scatter2: in-block LDS counting sort so staging writes stream out as
// contiguous runs per bucket (evidence R3->R4: fixed 4x write amplification).
// R11 LESSON (do not retry): CH=12288/SB=512 (1 block/CU, 120KB LDS) regressed
// scatter2 latency hiding AND coincided with a 2x h2pool codegen/variance
// regression -> net +129us. Keep CH=4096/256thr.
// rowfin: fused rowdeg+rowsort, IN-PLACE (sorted overlays stagingR): whole
// bucket staged in LDS ebuf, all reads complete before any write.
// Bucket size ~ Binomial(3.2M, 256/1e5): mean 8192, sigma 90; CAP=9216=+11sig.
// ORDERING: rowfin -> col_finalize (stagingC+dinv) -> h1 (regB over stagingC)
//           -> gather (sorted regA, h1b regB) -> h2pool.
// h2pool v2 (feature-per-lane): lane owns feature j=lane, weight columns in 64
// VGPRs -> ZERO LDS weight traffic (was 16KB/node broadcast reads, latency-
// bound at 17% occupancy); h1/p1 rows shfl-broadcast; pooled sums accumulate
// in registers; flush via 16 sbuf replicas (atomic contention /16).
// R8 LESSON (do not retry): block-per-bucket LDS-accumulating GATHER collapsed
// parallelism (391 blocks, 64 random loads in flight) -> 679us. Random-gather
// needs ~400K independent threads. rowfin/scatter2 only STREAM linearly.
#define NT 32              // col tiles (col < 2^17 -> tile = col>>12 in [0,32))
#define TILE_SHIFT 12      // 256KB h1b tiles -> gather window L2-resident
#define KEYS (256 * NT)    // row-sort bins: (rowlow, tile)
#define CAP 9216           // rowfin LDS staging capacity (entries per bucket)
#define H2B 512            // h2pool grid (2048 waves, grid-stride over nodes)
#define NREP 16            // sbuf replicas (atomic contention divider)

__device__ __forceinline__ void atomAddF(float* p, float v) {
    unsafeAtomicAdd(p, v);
}

// bf16 pack/unpack (round-to-nearest-even; finite values only)
__device__ __forceinline__ unsigned bf16rn(float f) {
    unsigned u = __float_as_uint(f);
    return (u + 0x7FFFu + ((u >> 16) & 1u)) >> 16;
}
__device__ __forceinline__ unsigned pack2(float a, float b) {
    return bf16rn(a) | (bf16rn(b) << 16);
}
__device__ __forceinline__ float blo(unsigned u) { return __uint_as_float(u << 16); }
__device__ __forceinline__ float bhi(unsigned u) { return __uint_as_float(u & 0xFFFF0000u); }

// wave-inclusive scan of v (64 lanes)
__device__ __forceinline__ int waveInclScan(int v, int lane) {
#pragma unroll
    for (int off = 1; off < 64; off <<= 1) {
        int u = __shfl_up(v, off);
        if (lane >= off) v += u;
    }
    return v;
}

// ---- phase 1: dual bucket histogram (row and col), block-aggregated -----
__global__ void hist2_kernel(const int* __restrict__ row, const int* __restrict__ col,
                             int* __restrict__ bhR, int* __restrict__ bhC, int E, int NB) {
    __shared__ int lhR[512];
    __shared__ int lhC[512];
    for (int t = threadIdx.x; t < 512; t += 256) { lhR[t] = 0; lhC[t] = 0; }
    __syncthreads();
    int base = blockIdx.x * CH;
    int end = min(base + CH, E);
    for (int e = base + threadIdx.x; e < end; e += 256) {
        atomicAdd(&lhR[row[e] >> 8], 1);
        atomicAdd(&lhC[col[e] >> 8], 1);
    }
    __syncthreads();
    for (int t = threadIdx.x; t < NB; t += 256) {
        if (lhR[t]) atomicAdd(&bhR[t * PAD], lhR[t]);
        if (lhC[t]) atomicAdd(&bhC[t * PAD], lhC[t]);
    }
}

// ---- phase 2: exclusive scan of bucket counts (NB <= 512), init cursors -
__global__ void bucket_scan_kernel(const int* __restrict__ bhist_p, int* __restrict__ bbase,
                                   int* __restrict__ bcursor_p, int* __restrict__ rowptr,
                                   int NB, int N, int E) {
    __shared__ int s[512];
    int t = threadIdx.x;
    int v = (t < NB) ? bhist_p[t * PAD] : 0;
    s[t] = v;
    __syncthreads();
    for (int off = 1; off < 512; off <<= 1) {
        int x = (t >= off) ? s[t - off] : 0;
        __syncthreads();
        s[t] += x;
        __syncthreads();
    }
    if (t < NB) { bbase[t] = s[t] - v; bcursor_p[t * PAD] = s[t] - v; }
    if (t == 0) { bbase[NB] = E; rowptr[N] = E; }
}

// ---- phase 3: dual scatter with in-block LDS counting sort --------------
// stagingR (row-bucketed): {col | rowlow<<24, attr}
// stagingC (col-bucketed): {row | collow<<24, attr}
__global__ void __launch_bounds__(256, 1)
scatter2_kernel(const int* __restrict__ row, const int* __restrict__ col,
                const float* __restrict__ attr,
                int* __restrict__ bcurR, int* __restrict__ bcurC,
                int2* __restrict__ stagingR, int2* __restrict__ stagingC,
                int E, int NB) {
    __shared__ int lh[512];
    __shared__ int lbase[512];
    __shared__ int loff[512];
    __shared__ int lcur[512];
    __shared__ int wsum[4];
    __shared__ int2 buf[CH];              // 32KB: block's edges grouped by bucket
    __shared__ unsigned short bkid[CH];   // 8KB: bucket id per entry
    int t = threadIdx.x;
    int lane = t & 63, wv = t >> 6;
    int base = blockIdx.x * CH;
    int end = min(base + CH, E);
    int cnt = end - base;

    for (int side = 0; side < 2; side++) {
        const int* key   = side ? col : row;
        const int* other = side ? row : col;
        int* bcur        = side ? bcurC : bcurR;
        int2* out        = side ? stagingC : stagingR;
        // hist
        for (int k = t; k < 512; k += 256) { lh[k] = 0; lcur[k] = 0; }
        __syncthreads();
        for (int e = base + t; e < end; e += 256)
            atomicAdd(&lh[key[e] >> 8], 1);
        __syncthreads();
        // reserve global runs
        for (int k = t; k < NB; k += 256)
            if (lh[k]) lbase[k] = atomicAdd(&bcur[k * PAD], lh[k]);
        // local exclusive scan of lh[0..511]: pair per thread, shfl wave scan
        int a0 = lh[2 * t], a1 = lh[2 * t + 1];
        int psum = a0 + a1;
        int incl = waveInclScan(psum, lane);
        if (lane == 63) wsum[wv] = incl;
        __syncthreads();
        int wadd = 0;
        for (int w = 0; w < wv; w++) wadd += wsum[w];
        int pexcl = incl + wadd - psum;
        loff[2 * t] = pexcl;
        loff[2 * t + 1] = pexcl + a0;
        __syncthreads();
        // place into LDS grouped by bucket
        for (int e = base + t; e < end; e += 256) {
            int k = key[e], o = other[e];
            int bk = k >> 8;
            int rank = atomicAdd(&lcur[bk], 1);
            int lpos = loff[bk] + rank;
            buf[lpos] = make_int2(o | ((k & 255) << 24), __float_as_int(attr[e]));
            bkid[lpos] = (unsigned short)bk;
        }
        __syncthreads();
        // coalesced write-out: consecutive j -> consecutive dst within runs
        for (int j = t; j < cnt; j += 256) {
            int bk = bkid[j];
            out[lbase[bk] + (j - loff[bk])] = buf[j];
        }
        __syncthreads();
    }
}

// ---- phase 4a: fused degree + counting sort, IN-PLACE -------------------
// Block b owns bucket b = rows [b*256, b*256+256) exclusively.
__global__ void __launch_bounds__(256, 1)
rowfin_kernel(const int* __restrict__ bbaseR, const int2* __restrict__ stagingR,
              int2* __restrict__ sorted /*aliases stagingR*/,
              int* __restrict__ rowptr, float* __restrict__ dinv, int N) {
    __shared__ int lcount[KEYS];      // 32KB: counts -> cursors
    __shared__ int2 ebuf[CAP];        // 72KB: sorted bucket staging
    __shared__ float ldeg[256];
    __shared__ float sdinv[256];
    __shared__ int wsum[4];
    int t = threadIdx.x;
    int lane = t & 63, wv = t >> 6;
    int b = blockIdx.x;
    int base = bbaseR[b], end = bbaseR[b + 1];
    int cnt = end - base;
    for (int k = t; k < KEYS; k += 256) lcount[k] = 0;
    ldeg[t] = 0.f;
    __syncthreads();
    // pass1: histogram + degree
    for (int e = base + t; e < end; e += 256) {
        int2 w = stagingR[e];
        int rl = (w.x >> 24) & 255;
        int tile = (w.x & 0xFFFFFF) >> TILE_SHIFT;
        atomicAdd(&lcount[rl * NT + tile], 1);
        atomicAdd(&ldeg[rl], __int_as_float(w.y));
    }
    __syncthreads();
    // per-row serial scan of NT bins; s = row total
    int vals[NT];
    int s = 0;
#pragma unroll
    for (int j = 0; j < NT; j++) { vals[j] = s; s += lcount[t * NT + j]; }
    int incl = waveInclScan(s, lane);
    if (lane == 63) wsum[wv] = incl;
    __syncthreads();
    int wadd = 0;
    for (int w = 0; w < wv; w++) wadd += wsum[w];
    int rowexcl = incl + wadd - s;
#pragma unroll
    for (int j = 0; j < NT; j++) lcount[t * NT + j] = rowexcl + vals[j];  // -> cursors
    int grow = (b << 8) + t;
    float d = ldeg[t];
    float di = d > 0.f ? rsqrtf(d) : 0.f;
    sdinv[t] = di;
    if (grow < N) {
        rowptr[grow] = base + rowexcl;
        dinv[grow] = di;
    }
    __syncthreads();
    // pass2: place into LDS at sorted position (reads L2-hot)
    for (int e = base + t; e < end; e += 256) {
        int2 w = stagingR[e];
        int rl = (w.x >> 24) & 255;
        int c = w.x & 0xFFFFFF;
        int key = rl * NT + (c >> TILE_SHIFT);
        int pos = atomicAdd(&lcount[key], 1);
        float pre = -sdinv[rl] * __int_as_float(w.y);
        int2 v = make_int2(c, __float_as_int(pre));
        if (pos < CAP) ebuf[pos] = v;
        else sorted[base + pos] = v;   // statistically impossible (>mean+11sigma)
    }
    __syncthreads();
    // pass3: linear stream-out over the block's own (fully-read) range
    int lim = min(cnt, CAP);
    for (int j = t; j < lim; j += 256)
        sorted[base + j] = ebuf[j];
}

// ---- phase 4b: per-col-bucket presum (NO global atomics) ----------------
// presum[c] = sum_{e: col=c} -dinv[row_e] * attr_e
// Runs after rowfin (needs dinv); MUST run before h1 (h1 overlays stagingC).
__global__ void col_finalize_kernel(const int* __restrict__ bbaseC,
                                    const int2* __restrict__ stagingC,
                                    const float* __restrict__ dinv,
                                    float* __restrict__ presum, int N) {
    __shared__ float bins[256];
    int t = threadIdx.x;
    int b = blockIdx.x;
    int base = bbaseC[b], end = bbaseC[b + 1];
    bins[t] = 0.f;
    __syncthreads();
    for (int e = base + t; e < end; e += 256) {
        int2 w = stagingC[e];
        int r = w.x & 0xFFFFFF;
        int cl = (w.x >> 24) & 255;
        float pre = -dinv[r] * __int_as_float(w.y);
        atomicAdd(&bins[cl], pre);   // LDS float atomic
    }
    __syncthreads();
    int grow = (b << 8) + t;
    if (grow < N) presum[grow] = bins[t];
}

// ---- h1 = leaky_relu(x @ w1 + b1); also h1b = bf16(dinv[i] * h1) --------
// h1b row = 32 bf16 = 64B = 4 uint4; feature 2k low half, 2k+1 high half.
__global__ void h1_kernel(const float* __restrict__ x, const float* __restrict__ w,
                          const float* __restrict__ b, const float* __restrict__ dinv,
                          float* __restrict__ h1, uint4* __restrict__ h1b, int N) {
    __shared__ float ws[20 * 32];
    __shared__ float bs[32];
    for (int t = threadIdx.x; t < 640; t += blockDim.x) ws[t] = w[t];
    if (threadIdx.x < 32) bs[threadIdx.x] = b[threadIdx.x];
    __syncthreads();
    int i = blockIdx.x * blockDim.x + threadIdx.x;
    if (i >= N) return;
    float xi[20];
#pragma unroll
    for (int k = 0; k < 20; k++) xi[k] = x[i * 20 + k];
    float acc[32];
#pragma unroll
    for (int j = 0; j < 32; j++) acc[j] = bs[j];
#pragma unroll
    for (int k = 0; k < 20; k++) {
        float a = xi[k];
#pragma unroll
        for (int j = 0; j < 32; j++) acc[j] += a * ws[k * 32 + j];
    }
#pragma unroll
    for (int j = 0; j < 32; j++) {
        float v = acc[j];
        acc[j] = v > 0.f ? v : v * NEG_SLOPE;
    }
    float4* h1v = (float4*)(h1 + (long)i * 32);
#pragma unroll
    for (int j4 = 0; j4 < 8; j4++)
        h1v[j4] = make_float4(acc[j4 * 4], acc[j4 * 4 + 1], acc[j4 * 4 + 2], acc[j4 * 4 + 3]);
    float di = dinv[i];
    unsigned u[16];
#pragma unroll
    for (int k = 0; k < 16; k++) u[k] = pack2(di * acc[2 * k], di * acc[2 * k + 1]);
#pragma unroll
    for (int q = 0; q < 4; q++)
        h1b[(long)i * 4 + q] = make_uint4(u[4 * q], u[4 * q + 1], u[4 * q + 2], u[4 * q + 3]);
}

// ---- pure gather-propagate (no atomics) ---------------------------------
// p1[i] = sum_{e in CSR row i} pre_e * h1b[col_e]   (dinv[col] baked into h1b)
// 4 threads per node, each owning 8 bf16 features (one uint4 = 64B/row total).
__global__ void gather_kernel(const int* __restrict__ rowptr, const int2* __restrict__ sorted,
                              const uint4* __restrict__ h1b, uint4* __restrict__ p1b, int N) {
    long idx = (long)blockIdx.x * blockDim.x + threadIdx.x;
    int node = (int)(idx >> 2);
    int part = (int)(idx & 3);
    if (node >= N) return;
    int s0 = rowptr[node], s1 = rowptr[node + 1];
    float acc[8];
#pragma unroll
    for (int k = 0; k < 8; k++) acc[k] = 0.f;
    int e = s0;
    for (; e + 4 <= s1; e += 4) {
        int2 q0 = sorted[e], q1 = sorted[e + 1], q2 = sorted[e + 2], q3 = sorted[e + 3];
        float n0 = __int_as_float(q0.y), n1 = __int_as_float(q1.y);
        float n2 = __int_as_float(q2.y), n3 = __int_as_float(q3.y);
        uint4 v0 = h1b[(long)q0.x * 4 + part];
        uint4 v1 = h1b[(long)q1.x * 4 + part];
        uint4 v2 = h1b[(long)q2.x * 4 + part];
        uint4 v3 = h1b[(long)q3.x * 4 + part];
        acc[0] += n0 * blo(v0.x) + n1 * blo(v1.x) + n2 * blo(v2.x) + n3 * blo(v3.x);
        acc[1] += n0 * bhi(v0.x) + n1 * bhi(v1.x) + n2 * bhi(v2.x) + n3 * bhi(v3.x);
        acc[2] += n0 * blo(v0.y) + n1 * blo(v1.y) + n2 * blo(v2.y) + n3 * blo(v3.y);
        acc[3] += n0 * bhi(v0.y) + n1 * bhi(v1.y) + n2 * bhi(v2.y) + n3 * bhi(v3.y);
        acc[4] += n0 * blo(v0.z) + n1 * blo(v1.z) + n2 * blo(v2.z) + n3 * blo(v3.z);
        acc[5] += n0 * bhi(v0.z) + n1 * bhi(v1.z) + n2 * bhi(v2.z) + n3 * bhi(v3.z);
        acc[6] += n0 * blo(v0.w) + n1 * blo(v1.w) + n2 * blo(v2.w) + n3 * blo(v3.w);
        acc[7] += n0 * bhi(v0.w) + n1 * bhi(v1.w) + n2 * bhi(v2.w) + n3 * bhi(v3.w);
    }
    for (; e < s1; e++) {
        int2 q = sorted[e];
        float nm = __int_as_float(q.y);
        uint4 v = h1b[(long)q.x * 4 + part];
        acc[0] += nm * blo(v.x); acc[1] += nm * bhi(v.x);
        acc[2] += nm * blo(v.y); acc[3] += nm * bhi(v.y);
        acc[4] += nm * blo(v.z); acc[5] += nm * bhi(v.z);
        acc[6] += nm * blo(v.w); acc[7] += nm * bhi(v.w);
    }
    p1b[(long)node * 4 + part] = make_uint4(pack2(acc[0], acc[1]), pack2(acc[2], acc[3]),
                                            pack2(acc[4], acc[5]), pack2(acc[6], acc[7]));
}

// ---- fused h2 + pooled sums, v2: feature-per-lane, weights in VGPRs -----
// Lane l owns output feature j=l. w0col/w1col (32 floats each) live in regs.
// Per node: h1 row (fp32) + p1 row (bf16 words) loaded coalesced per-lane,
// broadcast across the wave via shfl; h2[j] computed and pooled IN REGISTERS:
//   s1 += h2[j],  s2 += cw_i * h2[j].
// No LDS weight reads (was 16KB/node), no butterfly. Flush: LDS combine of 4
// waves -> atomics into sbuf replica (blockIdx & (NREP-1)).
__global__ void __launch_bounds__(256, 1)
h2pool_kernel(const float* __restrict__ h1, const uint4* __restrict__ p1b,
              const float* __restrict__ presum, const float* __restrict__ dinv,
              const float* __restrict__ w0, const float* __restrict__ w1,
              const float* __restrict__ b, float* __restrict__ sbuf, int N, int W) {
    __shared__ float wred[4][128];
    int t = threadIdx.x;
    int lane = t & 63, wv = t >> 6;
    float w0r[32], w1r[32];
#pragma unroll
    for (int k = 0; k < 32; k++) {
        w0r[k] = w0[k * 64 + lane];   // column j=lane of w2_0 (32x64 row-major)
        w1r[k] = w1[k * 64 + lane];
    }
    float bj = b[lane];
    const unsigned* p1w = (const unsigned*)p1b;
    float s1 = 0.f, s2 = 0.f;
    int gw = blockIdx.x * 4 + wv;     // global wave id; W = total waves
    for (int i = gw; i < N; i += W) {
        float hv = h1[(long)i * 32 + (lane & 31)];      // lanes 0-31 hold k=0..31
        unsigned pw = p1w[(long)i * 16 + (lane & 15)];  // lane m holds p1 word m
        float cwi = presum[i] * dinv[i];                // uniform -> broadcast
        float a0 = bj, a1 = 0.f, a2 = 0.f, a3 = 0.f;
#pragma unroll
        for (int k = 0; k < 32; k += 4) {
            float h0 = __shfl(hv, k);
            float h1f = __shfl(hv, k + 1);
            float h2f = __shfl(hv, k + 2);
            float h3f = __shfl(hv, k + 3);
            unsigned pA = __shfl(pw, k >> 1);       // p1 features k, k+1
            unsigned pB = __shfl(pw, (k >> 1) + 1); // p1 features k+2, k+3
            a0 += h0 * w0r[k]     + blo(pA) * w1r[k];
            a1 += h1f * w0r[k + 1] + bhi(pA) * w1r[k + 1];
            a2 += h2f * w0r[k + 2] + blo(pB) * w1r[k + 2];
            a3 += h3f * w0r[k + 3] + bhi(pB) * w1r[k + 3];
        }
        float v = (a0 + a1) + (a2 + a3);
        v = v > 0.f ? v : v * NEG_SLOPE;
        s1 += v;
        s2 += cwi * v;
    }
    wred[wv][lane] = s1;
    wred[wv][64 + lane] = s2;
    __syncthreads();
    if (t < 128) {
        float s = wred[0][t] + wred[1][t] + wred[2][t] + wred[3][t];
        atomAddF(&sbuf[(blockIdx.x & (NREP - 1)) * 128 + t], s);
    }
}

// ---- pooled = (s1/N)@w30 + (s2/N)@w31 + b3; out = log_softmax -----------
// 64 threads: thread k sums feature k across NREP replicas; thread 0 finishes.
__global__ void final_kernel(const float* __restrict__ sbuf,
                             const float* __restrict__ w30, const float* __restrict__ w31,
                             const float* __restrict__ b3, float* __restrict__ out, float invN) {
    __shared__ float s1s[64];
    __shared__ float s2s[64];
    int t = threadIdx.x;
    float s1 = 0.f, s2 = 0.f;
#pragma unroll
    for (int r = 0; r < NREP; r++) {
        s1 += sbuf[r * 128 + t];
        s2 += sbuf[r * 128 + 64 + t];
    }
    s1s[t] = s1;
    s2s[t] = s2;
    __syncthreads();
    if (t != 0) return;
    float p[2];
    for (int c = 0; c < 2; c++) {
        float a = 0.f;
        for (int k = 0; k < 64; k++) a += s1s[k] * w30[k * 2 + c] + s2s[k] * w31[k * 2 + c];
        p[c] = a * invN + b3[c];
    }
    float m = fmaxf(p[0], p[1]);
    float lse = m + logf(expf(p[0] - m) + expf(p[1] - m));
    out[0] = p[0] - lse;
    out[1] = p[1] - lse;
}

extern "C" void kernel_launch(void* const* d_in, const int* in_sizes, int n_in,
                              void* d_out, int out_size, void* d_ws, size_t ws_size,
                              hipStream_t stream) {
    const float* x    = (const float*)d_in[0];
    const int*   ei   = (const int*)d_in[1];
    const float* attr = (const float*)d_in[2];
    const float* w1_0 = (const float*)d_in[3];
    const float* b1   = (const float*)d_in[4];
    const float* w2_0 = (const float*)d_in[5];
    const float* w2_1 = (const float*)d_in[6];
    const float* b2   = (const float*)d_in[7];
    const float* w3_0 = (const float*)d_in[8];
    const float* w3_1 = (const float*)d_in[9];
    const float* b3   = (const float*)d_in[10];

    const int N = in_sizes[0] / 20;   // 100000
    const int E = in_sizes[2];        // 3200000
    const int* row = ei;
    const int* col = ei + E;
    const int NB = (N + 255) >> 8;    // 391 buckets (<= 512)

    // workspace layout (words)
    long big = (long)(2L * E > 64L * N ? 2L * E : 64L * N);
    float* ws = (float*)d_ws;
    float* dinv   = ws;                            // N
    float* presum = ws + N;                        // N
    int*   rowptr = (int*)(ws + 2L * N);           // N+1 (alloc N+4)
    long   off    = 3L * N + 4;
    int*   bhR    = (int*)(ws + off); off += 512L * PAD;   // row hist (padded)
    int*   bhC    = (int*)(ws + off); off += 512L * PAD;   // col hist (padded)
    int*   bbaseR = (int*)(ws + off); off += 516;
    int*   bbaseC = (int*)(ws + off); off += 516;
    int*   bcurR  = (int*)(ws + off); off += 512L * PAD;
    int*   bcurC  = (int*)(ws + off); off += 512L * PAD;
    float* sbuf   = ws + off;         off += NREP * 128;   // replicated pooled sums
    long   offA   = (off + 15) & ~15L;                     // 64B-align regA
    float* regA   = ws + offA;                  // big: stagingR -> sorted (in-place)
    float* regB   = regA + big;                 // big: stagingC -> h1+p1b+h1b

    int2*  stagingR = (int2*)regA;              // rewritten in-place as sorted
    int2*  sorted   = (int2*)regA;              // == stagingR region; dead after gather
    int2*  stagingC = (int2*)regB;              // dead after col_finalize
    float* h1       = regB;                     // fp32, 32N words (over stagingC)
    uint4* p1b      = (uint4*)(regB + 32L * N); // bf16, 16N words
    uint4* h1b      = (uint4*)(regB + 48L * N); // bf16 (dinv-scaled), 16N words

    // zero accumulated regions (ws is poisoned before every launch)
    hipMemsetAsync(bhR, 0, 2 * 512 * PAD * 4, stream);   // bhR + bhC contiguous
    hipMemsetAsync(sbuf, 0, NREP * 128 * 4, stream);

    const int B = 256;
    const int NCH = (E + CH - 1) / CH;   // chunk-blocks for hist/scatter
    hist2_kernel<<<NCH, B, 0, stream>>>(row, col, bhR, bhC, E, NB);
    bucket_scan_kernel<<<1, 512, 0, stream>>>(bhR, bbaseR, bcurR, rowptr, NB, N, E);
    bucket_scan_kernel<<<1, 512, 0, stream>>>(bhC, bbaseC, bcurC, rowptr, NB, N, E);
    scatter2_kernel<<<NCH, B, 0, stream>>>(row, col, attr, bcurR, bcurC, stagingR, stagingC, E, NB);
    rowfin_kernel<<<NB, 256, 0, stream>>>(bbaseR, stagingR, sorted, rowptr, dinv, N);  // in-place
    col_finalize_kernel<<<NB, 256, 0, stream>>>(bbaseC, stagingC, dinv, presum, N);    // frees regB
    h1_kernel<<<(N + B - 1) / B, B, 0, stream>>>(x, w1_0, b1, dinv, h1, h1b, N);
    {
        long t = (long)N * 4;
        gather_kernel<<<(int)((t + B - 1) / B), B, 0, stream>>>(rowptr, sorted, h1b, p1b, N);
    }
    h2pool_kernel<<<H2B, B, 0, stream>>>(h1, p1b, presum, dinv, w2_0, w2_1, b2, sbuf, N, H2B * 4);
    final_kernel<<<1, 64, 0, stream>>>(sbuf, w3_0, w3_1, b3, (float*)d_out, 1.0f / (float)N);
}

// Round 13
// 428.138 us; speedup vs baseline: 1.3367x; 1.0308x over previous
//
#include <hip/hip_runtime.h>
#include <hip/hip_bf16.h>
#include <hip/hip_fp8.h>

#define NEG_SLOPE 0.01f
#define CH 4096            // edges per block in hist/scatter (LDS-aggregated)
#define PAD 16             // 64B stride for contended global counters
// Dual bucket sort: row-bucketed CSR for the gather, col-bucketed staging for
// the presum (cw) aggregation -> NO per-edge global atomics anywhere.
// bucket id = id >> 8 (256 ids per bucket); NB = ceil(N/256) <= 512.
// Packing: {other_id (<2^24) | low8(key_id) << 24}.
// scatter2: in-block LDS counting sort so staging writes stream out as
// contiguous runs per bucket (evidence R3->R4: fixed 4x write amplification).
// R11 LESSON (do not retry): CH=12288/SB=512 (1 block/CU, 120KB LDS) regressed
// scatter2 latency hiding -> keep CH=4096/256thr. scatter2 ~99us is PARKED
// (pattern-bound: insensitive to occupancy 15->24%, VALU 4.6%).
// rowfin: fused rowdeg+rowsort, IN-PLACE (sorted overlays stagingR): whole
// bucket staged in LDS ebuf, all reads complete before any write.
// Bucket size ~ Binomial(3.2M, 256/1e5): mean 8192, sigma 90; CAP=9216=+11sig.
// ORDERING: rowfin -> col_finalize (stagingC+dinv) -> h1 (regB over stagingC)
//           -> gather (sorted regA, h1b regB) -> h2pool.
// h1b is FP8 e4m3 (OCP, gfx950-native): row = 32B -> gather footprint 3.2MB
// fits per-XCD L2 (was 6.4MB bf16 at ~72% hit). p1b stays bf16; accum fp32.
// h2pool v2 (feature-per-lane): weight columns in VGPRs, pooled sums in regs.
// R8 LESSON (do not retry): block-per-bucket LDS-accumulating GATHER collapsed
// parallelism (391 blocks, 64 random loads in flight) -> 679us. Random-gather
// needs ~400K independent threads. rowfin/scatter2 only STREAM linearly.
#define NT 32              // col tiles (col < 2^17 -> tile = col>>12 in [0,32))
#define TILE_SHIFT 12      // tile-sorted rows keep the gather window compact
#define KEYS (256 * NT)    // row-sort bins: (rowlow, tile)
#define CAP 9216           // rowfin LDS staging capacity (entries per bucket)
#define H2B 512            // h2pool grid (2048 waves, grid-stride over nodes)
#define NREP 16            // sbuf replicas (atomic contention divider)

__device__ __forceinline__ void atomAddF(float* p, float v) {
    unsafeAtomicAdd(p, v);
}

// bf16 pack/unpack (round-to-nearest-even; finite values only)
__device__ __forceinline__ unsigned bf16rn(float f) {
    unsigned u = __float_as_uint(f);
    return (u + 0x7FFFu + ((u >> 16) & 1u)) >> 16;
}
__device__ __forceinline__ unsigned pack2(float a, float b) {
    return bf16rn(a) | (bf16rn(b) << 16);
}
__device__ __forceinline__ float blo(unsigned u) { return __uint_as_float(u << 16); }
__device__ __forceinline__ float bhi(unsigned u) { return __uint_as_float(u & 0xFFFF0000u); }

// fp8 e4m3 (OCP) encode/decode via HIP type
__device__ __forceinline__ unsigned char e8(float f) {
    __hip_fp8_e4m3 q(f);
    return (unsigned char)q.__x;
}
__device__ __forceinline__ float d8(unsigned w, int b) {
    __hip_fp8_e4m3 q;
    q.__x = (__hip_fp8_storage_t)((w >> (b * 8)) & 0xFF);
    return (float)q;
}

// wave-inclusive scan of v (64 lanes)
__device__ __forceinline__ int waveInclScan(int v, int lane) {
#pragma unroll
    for (int off = 1; off < 64; off <<= 1) {
        int u = __shfl_up(v, off);
        if (lane >= off) v += u;
    }
    return v;
}

// ---- phase 1: dual bucket histogram (row and col), block-aggregated -----
__global__ void hist2_kernel(const int* __restrict__ row, const int* __restrict__ col,
                             int* __restrict__ bhR, int* __restrict__ bhC, int E, int NB) {
    __shared__ int lhR[512];
    __shared__ int lhC[512];
    for (int t = threadIdx.x; t < 512; t += 256) { lhR[t] = 0; lhC[t] = 0; }
    __syncthreads();
    int base = blockIdx.x * CH;
    int end = min(base + CH, E);
    for (int e = base + threadIdx.x; e < end; e += 256) {
        atomicAdd(&lhR[row[e] >> 8], 1);
        atomicAdd(&lhC[col[e] >> 8], 1);
    }
    __syncthreads();
    for (int t = threadIdx.x; t < NB; t += 256) {
        if (lhR[t]) atomicAdd(&bhR[t * PAD], lhR[t]);
        if (lhC[t]) atomicAdd(&bhC[t * PAD], lhC[t]);
    }
}

// ---- phase 2: exclusive scan of bucket counts (NB <= 512), init cursors -
__global__ void bucket_scan_kernel(const int* __restrict__ bhist_p, int* __restrict__ bbase,
                                   int* __restrict__ bcursor_p, int* __restrict__ rowptr,
                                   int NB, int N, int E) {
    __shared__ int s[512];
    int t = threadIdx.x;
    int v = (t < NB) ? bhist_p[t * PAD] : 0;
    s[t] = v;
    __syncthreads();
    for (int off = 1; off < 512; off <<= 1) {
        int x = (t >= off) ? s[t - off] : 0;
        __syncthreads();
        s[t] += x;
        __syncthreads();
    }
    if (t < NB) { bbase[t] = s[t] - v; bcursor_p[t * PAD] = s[t] - v; }
    if (t == 0) { bbase[NB] = E; rowptr[N] = E; }
}

// ---- phase 3: dual scatter with in-block LDS counting sort --------------
// stagingR (row-bucketed): {col | rowlow<<24, attr}
// stagingC (col-bucketed): {row | collow<<24, attr}
__global__ void __launch_bounds__(256, 1)
scatter2_kernel(const int* __restrict__ row, const int* __restrict__ col,
                const float* __restrict__ attr,
                int* __restrict__ bcurR, int* __restrict__ bcurC,
                int2* __restrict__ stagingR, int2* __restrict__ stagingC,
                int E, int NB) {
    __shared__ int lh[512];
    __shared__ int lbase[512];
    __shared__ int loff[512];
    __shared__ int lcur[512];
    __shared__ int wsum[4];
    __shared__ int2 buf[CH];              // 32KB: block's edges grouped by bucket
    __shared__ unsigned short bkid[CH];   // 8KB: bucket id per entry
    int t = threadIdx.x;
    int lane = t & 63, wv = t >> 6;
    int base = blockIdx.x * CH;
    int end = min(base + CH, E);
    int cnt = end - base;

    for (int side = 0; side < 2; side++) {
        const int* key   = side ? col : row;
        const int* other = side ? row : col;
        int* bcur        = side ? bcurC : bcurR;
        int2* out        = side ? stagingC : stagingR;
        // hist
        for (int k = t; k < 512; k += 256) { lh[k] = 0; lcur[k] = 0; }
        __syncthreads();
        for (int e = base + t; e < end; e += 256)
            atomicAdd(&lh[key[e] >> 8], 1);
        __syncthreads();
        // reserve global runs
        for (int k = t; k < NB; k += 256)
            if (lh[k]) lbase[k] = atomicAdd(&bcur[k * PAD], lh[k]);
        // local exclusive scan of lh[0..511]: pair per thread, shfl wave scan
        int a0 = lh[2 * t], a1 = lh[2 * t + 1];
        int psum = a0 + a1;
        int incl = waveInclScan(psum, lane);
        if (lane == 63) wsum[wv] = incl;
        __syncthreads();
        int wadd = 0;
        for (int w = 0; w < wv; w++) wadd += wsum[w];
        int pexcl = incl + wadd - psum;
        loff[2 * t] = pexcl;
        loff[2 * t + 1] = pexcl + a0;
        __syncthreads();
        // place into LDS grouped by bucket
        for (int e = base + t; e < end; e += 256) {
            int k = key[e], o = other[e];
            int bk = k >> 8;
            int rank = atomicAdd(&lcur[bk], 1);
            int lpos = loff[bk] + rank;
            buf[lpos] = make_int2(o | ((k & 255) << 24), __float_as_int(attr[e]));
            bkid[lpos] = (unsigned short)bk;
        }
        __syncthreads();
        // coalesced write-out: consecutive j -> consecutive dst within runs
        for (int j = t; j < cnt; j += 256) {
            int bk = bkid[j];
            out[lbase[bk] + (j - loff[bk])] = buf[j];
        }
        __syncthreads();
    }
}

// ---- phase 4a: fused degree + counting sort, IN-PLACE -------------------
// Block b owns bucket b = rows [b*256, b*256+256) exclusively.
__global__ void __launch_bounds__(256, 1)
rowfin_kernel(const int* __restrict__ bbaseR, const int2* __restrict__ stagingR,
              int2* __restrict__ sorted /*aliases stagingR*/,
              int* __restrict__ rowptr, float* __restrict__ dinv, int N) {
    __shared__ int lcount[KEYS];      // 32KB: counts -> cursors
    __shared__ int2 ebuf[CAP];        // 72KB: sorted bucket staging
    __shared__ float ldeg[256];
    __shared__ float sdinv[256];
    __shared__ int wsum[4];
    int t = threadIdx.x;
    int lane = t & 63, wv = t >> 6;
    int b = blockIdx.x;
    int base = bbaseR[b], end = bbaseR[b + 1];
    int cnt = end - base;
    for (int k = t; k < KEYS; k += 256) lcount[k] = 0;
    ldeg[t] = 0.f;
    __syncthreads();
    // pass1: histogram + degree
    for (int e = base + t; e < end; e += 256) {
        int2 w = stagingR[e];
        int rl = (w.x >> 24) & 255;
        int tile = (w.x & 0xFFFFFF) >> TILE_SHIFT;
        atomicAdd(&lcount[rl * NT + tile], 1);
        atomicAdd(&ldeg[rl], __int_as_float(w.y));
    }
    __syncthreads();
    // per-row serial scan of NT bins; s = row total
    int vals[NT];
    int s = 0;
#pragma unroll
    for (int j = 0; j < NT; j++) { vals[j] = s; s += lcount[t * NT + j]; }
    int incl = waveInclScan(s, lane);
    if (lane == 63) wsum[wv] = incl;
    __syncthreads();
    int wadd = 0;
    for (int w = 0; w < wv; w++) wadd += wsum[w];
    int rowexcl = incl + wadd - s;
#pragma unroll
    for (int j = 0; j < NT; j++) lcount[t * NT + j] = rowexcl + vals[j];  // -> cursors
    int grow = (b << 8) + t;
    float d = ldeg[t];
    float di = d > 0.f ? rsqrtf(d) : 0.f;
    sdinv[t] = di;
    if (grow < N) {
        rowptr[grow] = base + rowexcl;
        dinv[grow] = di;
    }
    __syncthreads();
    // pass2: place into LDS at sorted position (reads L2-hot)
    for (int e = base + t; e < end; e += 256) {
        int2 w = stagingR[e];
        int rl = (w.x >> 24) & 255;
        int c = w.x & 0xFFFFFF;
        int key = rl * NT + (c >> TILE_SHIFT);
        int pos = atomicAdd(&lcount[key], 1);
        float pre = -sdinv[rl] * __int_as_float(w.y);
        int2 v = make_int2(c, __float_as_int(pre));
        if (pos < CAP) ebuf[pos] = v;
        else sorted[base + pos] = v;   // statistically impossible (>mean+11sigma)
    }
    __syncthreads();
    // pass3: linear stream-out over the block's own (fully-read) range
    int lim = min(cnt, CAP);
    for (int j = t; j < lim; j += 256)
        sorted[base + j] = ebuf[j];
}

// ---- phase 4b: per-col-bucket presum (NO global atomics) ----------------
// presum[c] = sum_{e: col=c} -dinv[row_e] * attr_e
// Runs after rowfin (needs dinv); MUST run before h1 (h1 overlays stagingC).
__global__ void col_finalize_kernel(const int* __restrict__ bbaseC,
                                    const int2* __restrict__ stagingC,
                                    const float* __restrict__ dinv,
                                    float* __restrict__ presum, int N) {
    __shared__ float bins[256];
    int t = threadIdx.x;
    int b = blockIdx.x;
    int base = bbaseC[b], end = bbaseC[b + 1];
    bins[t] = 0.f;
    __syncthreads();
    for (int e = base + t; e < end; e += 256) {
        int2 w = stagingC[e];
        int r = w.x & 0xFFFFFF;
        int cl = (w.x >> 24) & 255;
        float pre = -dinv[r] * __int_as_float(w.y);
        atomicAdd(&bins[cl], pre);   // LDS float atomic
    }
    __syncthreads();
    int grow = (b << 8) + t;
    if (grow < N) presum[grow] = bins[t];
}

// ---- h1 = leaky_relu(x @ w1 + b1); also h1q = fp8(dinv[i] * h1) ---------
// h1q row = 32 fp8 = 32B = 2 uint4; byte j = feature j (natural order).
__global__ void h1_kernel(const float* __restrict__ x, const float* __restrict__ w,
                          const float* __restrict__ b, const float* __restrict__ dinv,
                          float* __restrict__ h1, uint4* __restrict__ h1q, int N) {
    __shared__ float ws[20 * 32];
    __shared__ float bs[32];
    for (int t = threadIdx.x; t < 640; t += blockDim.x) ws[t] = w[t];
    if (threadIdx.x < 32) bs[threadIdx.x] = b[threadIdx.x];
    __syncthreads();
    int i = blockIdx.x * blockDim.x + threadIdx.x;
    if (i >= N) return;
    float xi[20];
#pragma unroll
    for (int k = 0; k < 20; k++) xi[k] = x[i * 20 + k];
    float acc[32];
#pragma unroll
    for (int j = 0; j < 32; j++) acc[j] = bs[j];
#pragma unroll
    for (int k = 0; k < 20; k++) {
        float a = xi[k];
#pragma unroll
        for (int j = 0; j < 32; j++) acc[j] += a * ws[k * 32 + j];
    }
#pragma unroll
    for (int j = 0; j < 32; j++) {
        float v = acc[j];
        acc[j] = v > 0.f ? v : v * NEG_SLOPE;
    }
    float4* h1v = (float4*)(h1 + (long)i * 32);
#pragma unroll
    for (int j4 = 0; j4 < 8; j4++)
        h1v[j4] = make_float4(acc[j4 * 4], acc[j4 * 4 + 1], acc[j4 * 4 + 2], acc[j4 * 4 + 3]);
    float di = dinv[i];
    unsigned wds[8];
#pragma unroll
    for (int wq = 0; wq < 8; wq++) {
        unsigned wd = 0;
#pragma unroll
        for (int j = 0; j < 4; j++)
            wd |= (unsigned)e8(di * acc[wq * 4 + j]) << (8 * j);
        wds[wq] = wd;
    }
    h1q[(long)i * 2 + 0] = make_uint4(wds[0], wds[1], wds[2], wds[3]);
    h1q[(long)i * 2 + 1] = make_uint4(wds[4], wds[5], wds[6], wds[7]);
}

// ---- pure gather-propagate (no atomics), fp8 operand --------------------
// p1[i] = sum_{e in CSR row i} pre_e * h1q[col_e]   (dinv[col] baked into h1q)
// 4 threads per node, each owning 8 fp8 features (one uint2 = 32B/row total).
__global__ void gather_kernel(const int* __restrict__ rowptr, const int2* __restrict__ sorted,
                              const uint2* __restrict__ h1q, uint4* __restrict__ p1b, int N) {
    long idx = (long)blockIdx.x * blockDim.x + threadIdx.x;
    int node = (int)(idx >> 2);
    int part = (int)(idx & 3);
    if (node >= N) return;
    int s0 = rowptr[node], s1 = rowptr[node + 1];
    float acc[8];
#pragma unroll
    for (int k = 0; k < 8; k++) acc[k] = 0.f;
    int e = s0;
    for (; e + 4 <= s1; e += 4) {
        int2 q0 = sorted[e], q1 = sorted[e + 1], q2 = sorted[e + 2], q3 = sorted[e + 3];
        float n0 = __int_as_float(q0.y), n1 = __int_as_float(q1.y);
        float n2 = __int_as_float(q2.y), n3 = __int_as_float(q3.y);
        uint2 v0 = h1q[(long)q0.x * 4 + part];
        uint2 v1 = h1q[(long)q1.x * 4 + part];
        uint2 v2 = h1q[(long)q2.x * 4 + part];
        uint2 v3 = h1q[(long)q3.x * 4 + part];
#pragma unroll
        for (int j = 0; j < 4; j++) {
            acc[j]     += n0 * d8(v0.x, j) + n1 * d8(v1.x, j) + n2 * d8(v2.x, j) + n3 * d8(v3.x, j);
            acc[4 + j] += n0 * d8(v0.y, j) + n1 * d8(v1.y, j) + n2 * d8(v2.y, j) + n3 * d8(v3.y, j);
        }
    }
    for (; e < s1; e++) {
        int2 q = sorted[e];
        float nm = __int_as_float(q.y);
        uint2 v = h1q[(long)q.x * 4 + part];
#pragma unroll
        for (int j = 0; j < 4; j++) {
            acc[j]     += nm * d8(v.x, j);
            acc[4 + j] += nm * d8(v.y, j);
        }
    }
    // p1b keeps the bf16 pair layout: word w holds features (2w, 2w+1).
    p1b[(long)node * 4 + part] = make_uint4(pack2(acc[0], acc[1]), pack2(acc[2], acc[3]),
                                            pack2(acc[4], acc[5]), pack2(acc[6], acc[7]));
}

// ---- fused h2 + pooled sums, v2: feature-per-lane, weights in VGPRs -----
// Lane l owns output feature j=l. w0col/w1col (32 floats each) live in regs.
__global__ void __launch_bounds__(256, 1)
h2pool_kernel(const float* __restrict__ h1, const uint4* __restrict__ p1b,
              const float* __restrict__ presum, const float* __restrict__ dinv,
              const float* __restrict__ w0, const float* __restrict__ w1,
              const float* __restrict__ b, float* __restrict__ sbuf, int N, int W) {
    __shared__ float wred[4][128];
    int t = threadIdx.x;
    int lane = t & 63, wv = t >> 6;
    float w0r[32], w1r[32];
#pragma unroll
    for (int k = 0; k < 32; k++) {
        w0r[k] = w0[k * 64 + lane];   // column j=lane of w2_0 (32x64 row-major)
        w1r[k] = w1[k * 64 + lane];
    }
    float bj = b[lane];
    const unsigned* p1w = (const unsigned*)p1b;
    float s1 = 0.f, s2 = 0.f;
    int gw = blockIdx.x * 4 + wv;     // global wave id; W = total waves
    for (int i = gw; i < N; i += W) {
        float hv = h1[(long)i * 32 + (lane & 31)];      // lanes 0-31 hold k=0..31
        unsigned pw = p1w[(long)i * 16 + (lane & 15)];  // lane m holds p1 word m
        float cwi = presum[i] * dinv[i];                // uniform -> broadcast
        float a0 = bj, a1 = 0.f, a2 = 0.f, a3 = 0.f;
#pragma unroll
        for (int k = 0; k < 32; k += 4) {
            float h0 = __shfl(hv, k);
            float h1f = __shfl(hv, k + 1);
            float h2f = __shfl(hv, k + 2);
            float h3f = __shfl(hv, k + 3);
            unsigned pA = __shfl(pw, k >> 1);       // p1 features k, k+1
            unsigned pB = __shfl(pw, (k >> 1) + 1); // p1 features k+2, k+3
            a0 += h0 * w0r[k]     + blo(pA) * w1r[k];
            a1 += h1f * w0r[k + 1] + bhi(pA) * w1r[k + 1];
            a2 += h2f * w0r[k + 2] + blo(pB) * w1r[k + 2];
            a3 += h3f * w0r[k + 3] + bhi(pB) * w1r[k + 3];
        }
        float v = (a0 + a1) + (a2 + a3);
        v = v > 0.f ? v : v * NEG_SLOPE;
        s1 += v;
        s2 += cwi * v;
    }
    wred[wv][lane] = s1;
    wred[wv][64 + lane] = s2;
    __syncthreads();
    if (t < 128) {
        float s = wred[0][t] + wred[1][t] + wred[2][t] + wred[3][t];
        atomAddF(&sbuf[(blockIdx.x & (NREP - 1)) * 128 + t], s);
    }
}

// ---- pooled = (s1/N)@w30 + (s2/N)@w31 + b3; out = log_softmax -----------
__global__ void final_kernel(const float* __restrict__ sbuf,
                             const float* __restrict__ w30, const float* __restrict__ w31,
                             const float* __restrict__ b3, float* __restrict__ out, float invN) {
    __shared__ float s1s[64];
    __shared__ float s2s[64];
    int t = threadIdx.x;
    float s1 = 0.f, s2 = 0.f;
#pragma unroll
    for (int r = 0; r < NREP; r++) {
        s1 += sbuf[r * 128 + t];
        s2 += sbuf[r * 128 + 64 + t];
    }
    s1s[t] = s1;
    s2s[t] = s2;
    __syncthreads();
    if (t != 0) return;
    float p[2];
    for (int c = 0; c < 2; c++) {
        float a = 0.f;
        for (int k = 0; k < 64; k++) a += s1s[k] * w30[k * 2 + c] + s2s[k] * w31[k * 2 + c];
        p[c] = a * invN + b3[c];
    }
    float m = fmaxf(p[0], p[1]);
    float lse = m + logf(expf(p[0] - m) + expf(p[1] - m));
    out[0] = p[0] - lse;
    out[1] = p[1] - lse;
}

extern "C" void kernel_launch(void* const* d_in, const int* in_sizes, int n_in,
                              void* d_out, int out_size, void* d_ws, size_t ws_size,
                              hipStream_t stream) {
    const float* x    = (const float*)d_in[0];
    const int*   ei   = (const int*)d_in[1];
    const float* attr = (const float*)d_in[2];
    const float* w1_0 = (const float*)d_in[3];
    const float* b1   = (const float*)d_in[4];
    const float* w2_0 = (const float*)d_in[5];
    const float* w2_1 = (const float*)d_in[6];
    const float* b2   = (const float*)d_in[7];
    const float* w3_0 = (const float*)d_in[8];
    const float* w3_1 = (const float*)d_in[9];
    const float* b3   = (const float*)d_in[10];

    const int N = in_sizes[0] / 20;   // 100000
    const int E = in_sizes[2];        // 3200000
    const int* row = ei;
    const int* col = ei + E;
    const int NB = (N + 255) >> 8;    // 391 buckets (<= 512)

    // workspace layout (words)
    long big = (long)(2L * E > 64L * N ? 2L * E : 64L * N);
    float* ws = (float*)d_ws;
    float* dinv   = ws;                            // N
    float* presum = ws + N;                        // N
    int*   rowptr = (int*)(ws + 2L * N);           // N+1 (alloc N+4)
    long   off    = 3L * N + 4;
    int*   bhR    = (int*)(ws + off); off += 512L * PAD;   // row hist (padded)
    int*   bhC    = (int*)(ws + off); off += 512L * PAD;   // col hist (padded)
    int*   bbaseR = (int*)(ws + off); off += 516;
    int*   bbaseC = (int*)(ws + off); off += 516;
    int*   bcurR  = (int*)(ws + off); off += 512L * PAD;
    int*   bcurC  = (int*)(ws + off); off += 512L * PAD;
    float* sbuf   = ws + off;         off += NREP * 128;   // replicated pooled sums
    long   offA   = (off + 15) & ~15L;                     // 64B-align regA
    float* regA   = ws + offA;                  // big: stagingR -> sorted (in-place)
    float* regB   = regA + big;                 // big: stagingC -> h1+p1b+h1q

    int2*  stagingR = (int2*)regA;              // rewritten in-place as sorted
    int2*  sorted   = (int2*)regA;              // == stagingR region; dead after gather
    int2*  stagingC = (int2*)regB;              // dead after col_finalize
    float* h1       = regB;                     // fp32, 32N words (over stagingC)
    uint4* p1b      = (uint4*)(regB + 32L * N); // bf16, 16N words
    uint4* h1q      = (uint4*)(regB + 48L * N); // fp8 (dinv-scaled), 8N words

    // zero accumulated regions (ws is poisoned before every launch)
    hipMemsetAsync(bhR, 0, 2 * 512 * PAD * 4, stream);   // bhR + bhC contiguous
    hipMemsetAsync(sbuf, 0, NREP * 128 * 4, stream);

    const int B = 256;
    const int NCH = (E + CH - 1) / CH;   // chunk-blocks for hist/scatter
    hist2_kernel<<<NCH, B, 0, stream>>>(row, col, bhR, bhC, E, NB);
    bucket_scan_kernel<<<1, 512, 0, stream>>>(bhR, bbaseR, bcurR, rowptr, NB, N, E);
    bucket_scan_kernel<<<1, 512, 0, stream>>>(bhC, bbaseC, bcurC, rowptr, NB, N, E);
    scatter2_kernel<<<NCH, B, 0, stream>>>(row, col, attr, bcurR, bcurC, stagingR, stagingC, E, NB);
    rowfin_kernel<<<NB, 256, 0, stream>>>(bbaseR, stagingR, sorted, rowptr, dinv, N);  // in-place
    col_finalize_kernel<<<NB, 256, 0, stream>>>(bbaseC, stagingC, dinv, presum, N);    // frees regB
    h1_kernel<<<(N + B - 1) / B, B, 0, stream>>>(x, w1_0, b1, dinv, h1, h1q, N);
    {
        long t = (long)N * 4;
        gather_kernel<<<(int)((t + B - 1) / B), B, 0, stream>>>(rowptr, sorted, (const uint2*)h1q, p1b, N);
    }
    h2pool_kernel<<<H2B, B, 0, stream>>>(h1, p1b, presum, dinv, w2_0, w2_1, b2, sbuf, N, H2B * 4);
    final_kernel<<<1, 64, 0, stream>>>(sbuf, w3_0, w3_1, b3, (float*)d_out, 1.0f / (float)N);
}

// Round 14
// 404.178 us; speedup vs baseline: 1.4159x; 1.0593x over previous
//
#include <hip/hip_runtime.h>
#include <hip/hip_bf16.h>
#include <hip/hip_fp8.h>

#define NEG_SLOPE 0.01f
#define CH 4096            // edges per block in hist/scatter (LDS-aggregated)
#define PAD 16             // 64B stride for contended global counters
// Dual bucket sort: row-bucketed CSR for the gather, col-bucketed staging for
// the presum (cw) aggregation -> NO per-edge global atomics anywhere.
// bucket id = id >> 8 (256 ids per bucket); NB = ceil(N/256) <= 512.
// Packing: {other_id (<2^24) | low8(key_id) << 24}.
// scatter2: in-block LDS counting sort so staging writes stream out as
// contiguous runs per bucket (evidence R3->R4: fixed 4x write amplification).
// R11 LESSON (do not retry): CH=12288/SB=512 regressed. scatter2 ~97us PARKED
// (pattern-bound; occupancy-insensitive; geometry at CH=4096 is the 3-block/CU
// optimum). R11's h2pool-189us anomaly: v1 always ran 391 blocks (17% occ);
// 2x swing was container variance -> v2 grid-strides 2048 waves.
// rowfin: fused rowdeg+rowsort, IN-PLACE (sorted overlays stagingR): whole
// bucket staged in LDS ebuf, all reads complete before any write.
// Bucket size ~ Binomial(3.2M, 256/1e5): mean 8192, sigma 90; CAP=9216=+11sig.
// ORDERING: rowfin -> col_finalize (stagingC+dinv) -> h1 (regB over stagingC)
//           -> gather (sorted regA, h1q regB) -> h2pool.
// h1q is FP8 e4m3 (row 32B): gather footprint 3.2MB, L2-resident (R13: -13us).
// h1 kept ONLY as bf16 pairs (h2pool's sole stream); p1b bf16; accum fp32.
// h2pool v2 (feature-per-lane): weight columns in VGPRs, pooled sums in regs.
// R8 LESSON (do not retry): block-per-bucket LDS-accumulating GATHER collapsed
// parallelism -> 679us. Random-gather needs ~400K independent threads.
#define NT 32              // col tiles (col < 2^17 -> tile = col>>12 in [0,32))
#define TILE_SHIFT 12      // tile-sorted rows keep the gather window compact
#define KEYS (256 * NT)    // row-sort bins: (rowlow, tile)
#define CAP 9216           // rowfin LDS staging capacity (entries per bucket)
#define H2B 512            // h2pool grid (2048 waves, grid-stride over nodes)
#define NREP 16            // sbuf replicas (atomic contention divider)

__device__ __forceinline__ void atomAddF(float* p, float v) {
    unsafeAtomicAdd(p, v);
}

// bf16 pack/unpack (round-to-nearest-even; finite values only)
__device__ __forceinline__ unsigned bf16rn(float f) {
    unsigned u = __float_as_uint(f);
    return (u + 0x7FFFu + ((u >> 16) & 1u)) >> 16;
}
__device__ __forceinline__ unsigned pack2(float a, float b) {
    return bf16rn(a) | (bf16rn(b) << 16);
}
__device__ __forceinline__ float blo(unsigned u) { return __uint_as_float(u << 16); }
__device__ __forceinline__ float bhi(unsigned u) { return __uint_as_float(u & 0xFFFF0000u); }

// fp8 e4m3 (OCP) encode/decode via HIP type
__device__ __forceinline__ unsigned char e8(float f) {
    __hip_fp8_e4m3 q(f);
    return (unsigned char)q.__x;
}
__device__ __forceinline__ float d8(unsigned w, int b) {
    __hip_fp8_e4m3 q;
    q.__x = (__hip_fp8_storage_t)((w >> (b * 8)) & 0xFF);
    return (float)q;
}

// wave-inclusive scan of v (64 lanes)
__device__ __forceinline__ int waveInclScan(int v, int lane) {
#pragma unroll
    for (int off = 1; off < 64; off <<= 1) {
        int u = __shfl_up(v, off);
        if (lane >= off) v += u;
    }
    return v;
}

// ---- phase 1: dual bucket histogram (row and col), block-aggregated -----
__global__ void hist2_kernel(const int* __restrict__ row, const int* __restrict__ col,
                             int* __restrict__ bhR, int* __restrict__ bhC, int E, int NB) {
    __shared__ int lhR[512];
    __shared__ int lhC[512];
    for (int t = threadIdx.x; t < 512; t += 256) { lhR[t] = 0; lhC[t] = 0; }
    __syncthreads();
    int base = blockIdx.x * CH;
    int end = min(base + CH, E);
    for (int e = base + threadIdx.x; e < end; e += 256) {
        atomicAdd(&lhR[row[e] >> 8], 1);
        atomicAdd(&lhC[col[e] >> 8], 1);
    }
    __syncthreads();
    for (int t = threadIdx.x; t < NB; t += 256) {
        if (lhR[t]) atomicAdd(&bhR[t * PAD], lhR[t]);
        if (lhC[t]) atomicAdd(&bhC[t * PAD], lhC[t]);
    }
}

// ---- phase 2: exclusive scans of both bucket-count arrays (one launch) --
// block 0: R side (+ rowptr[N] = E); block 1: C side.
__global__ void bucket_scan2_kernel(const int* __restrict__ bhR, const int* __restrict__ bhC,
                                    int* __restrict__ bbaseR, int* __restrict__ bbaseC,
                                    int* __restrict__ bcurR, int* __restrict__ bcurC,
                                    int* __restrict__ rowptr, int NB, int N, int E) {
    const int* bh = blockIdx.x ? bhC : bhR;
    int* bbase    = blockIdx.x ? bbaseC : bbaseR;
    int* bcur     = blockIdx.x ? bcurC : bcurR;
    __shared__ int s[512];
    int t = threadIdx.x;
    int v = (t < NB) ? bh[t * PAD] : 0;
    s[t] = v;
    __syncthreads();
    for (int off = 1; off < 512; off <<= 1) {
        int x = (t >= off) ? s[t - off] : 0;
        __syncthreads();
        s[t] += x;
        __syncthreads();
    }
    if (t < NB) { bbase[t] = s[t] - v; bcur[t * PAD] = s[t] - v; }
    if (t == 0) {
        bbase[NB] = E;
        if (blockIdx.x == 0) rowptr[N] = E;
    }
}

// ---- phase 3: dual scatter with in-block LDS counting sort --------------
// stagingR (row-bucketed): {col | rowlow<<24, attr}
// stagingC (col-bucketed): {row | collow<<24, attr}
__global__ void __launch_bounds__(256, 1)
scatter2_kernel(const int* __restrict__ row, const int* __restrict__ col,
                const float* __restrict__ attr,
                int* __restrict__ bcurR, int* __restrict__ bcurC,
                int2* __restrict__ stagingR, int2* __restrict__ stagingC,
                int E, int NB) {
    __shared__ int lh[512];
    __shared__ int lbase[512];
    __shared__ int loff[512];
    __shared__ int lcur[512];
    __shared__ int wsum[4];
    __shared__ int2 buf[CH];              // 32KB: block's edges grouped by bucket
    __shared__ unsigned short bkid[CH];   // 8KB: bucket id per entry
    int t = threadIdx.x;
    int lane = t & 63, wv = t >> 6;
    int base = blockIdx.x * CH;
    int end = min(base + CH, E);
    int cnt = end - base;

    for (int side = 0; side < 2; side++) {
        const int* key   = side ? col : row;
        const int* other = side ? row : col;
        int* bcur        = side ? bcurC : bcurR;
        int2* out        = side ? stagingC : stagingR;
        // hist
        for (int k = t; k < 512; k += 256) { lh[k] = 0; lcur[k] = 0; }
        __syncthreads();
        for (int e = base + t; e < end; e += 256)
            atomicAdd(&lh[key[e] >> 8], 1);
        __syncthreads();
        // reserve global runs
        for (int k = t; k < NB; k += 256)
            if (lh[k]) lbase[k] = atomicAdd(&bcur[k * PAD], lh[k]);
        // local exclusive scan of lh[0..511]: pair per thread, shfl wave scan
        int a0 = lh[2 * t], a1 = lh[2 * t + 1];
        int psum = a0 + a1;
        int incl = waveInclScan(psum, lane);
        if (lane == 63) wsum[wv] = incl;
        __syncthreads();
        int wadd = 0;
        for (int w = 0; w < wv; w++) wadd += wsum[w];
        int pexcl = incl + wadd - psum;
        loff[2 * t] = pexcl;
        loff[2 * t + 1] = pexcl + a0;
        __syncthreads();
        // place into LDS grouped by bucket
        for (int e = base + t; e < end; e += 256) {
            int k = key[e], o = other[e];
            int bk = k >> 8;
            int rank = atomicAdd(&lcur[bk], 1);
            int lpos = loff[bk] + rank;
            buf[lpos] = make_int2(o | ((k & 255) << 24), __float_as_int(attr[e]));
            bkid[lpos] = (unsigned short)bk;
        }
        __syncthreads();
        // coalesced write-out: consecutive j -> consecutive dst within runs
        for (int j = t; j < cnt; j += 256) {
            int bk = bkid[j];
            out[lbase[bk] + (j - loff[bk])] = buf[j];
        }
        __syncthreads();
    }
}

// ---- phase 4a: fused degree + counting sort, IN-PLACE -------------------
// Block b owns bucket b = rows [b*256, b*256+256) exclusively.
__global__ void __launch_bounds__(256, 1)
rowfin_kernel(const int* __restrict__ bbaseR, const int2* __restrict__ stagingR,
              int2* __restrict__ sorted /*aliases stagingR*/,
              int* __restrict__ rowptr, float* __restrict__ dinv, int N) {
    __shared__ int lcount[KEYS];      // 32KB: counts -> cursors
    __shared__ int2 ebuf[CAP];        // 72KB: sorted bucket staging
    __shared__ float ldeg[256];
    __shared__ float sdinv[256];
    __shared__ int wsum[4];
    int t = threadIdx.x;
    int lane = t & 63, wv = t >> 6;
    int b = blockIdx.x;
    int base = bbaseR[b], end = bbaseR[b + 1];
    int cnt = end - base;
    for (int k = t; k < KEYS; k += 256) lcount[k] = 0;
    ldeg[t] = 0.f;
    __syncthreads();
    // pass1: histogram + degree
    for (int e = base + t; e < end; e += 256) {
        int2 w = stagingR[e];
        int rl = (w.x >> 24) & 255;
        int tile = (w.x & 0xFFFFFF) >> TILE_SHIFT;
        atomicAdd(&lcount[rl * NT + tile], 1);
        atomicAdd(&ldeg[rl], __int_as_float(w.y));
    }
    __syncthreads();
    // per-row serial scan of NT bins; s = row total
    int vals[NT];
    int s = 0;
#pragma unroll
    for (int j = 0; j < NT; j++) { vals[j] = s; s += lcount[t * NT + j]; }
    int incl = waveInclScan(s, lane);
    if (lane == 63) wsum[wv] = incl;
    __syncthreads();
    int wadd = 0;
    for (int w = 0; w < wv; w++) wadd += wsum[w];
    int rowexcl = incl + wadd - s;
#pragma unroll
    for (int j = 0; j < NT; j++) lcount[t * NT + j] = rowexcl + vals[j];  // -> cursors
    int grow = (b << 8) + t;
    float d = ldeg[t];
    float di = d > 0.f ? rsqrtf(d) : 0.f;
    sdinv[t] = di;
    if (grow < N) {
        rowptr[grow] = base + rowexcl;
        dinv[grow] = di;
    }
    __syncthreads();
    // pass2: place into LDS at sorted position (reads L2-hot)
    for (int e = base + t; e < end; e += 256) {
        int2 w = stagingR[e];
        int rl = (w.x >> 24) & 255;
        int c = w.x & 0xFFFFFF;
        int key = rl * NT + (c >> TILE_SHIFT);
        int pos = atomicAdd(&lcount[key], 1);
        float pre = -sdinv[rl] * __int_as_float(w.y);
        int2 v = make_int2(c, __float_as_int(pre));
        if (pos < CAP) ebuf[pos] = v;
        else sorted[base + pos] = v;   // statistically impossible (>mean+11sigma)
    }
    __syncthreads();
    // pass3: linear stream-out over the block's own (fully-read) range
    int lim = min(cnt, CAP);
    for (int j = t; j < lim; j += 256)
        sorted[base + j] = ebuf[j];
}

// ---- phase 4b: per-col-bucket presum (NO global atomics) ----------------
// presum[c] = sum_{e: col=c} -dinv[row_e] * attr_e
// Runs after rowfin (needs dinv); MUST run before h1 (h1 overlays stagingC).
__global__ void col_finalize_kernel(const int* __restrict__ bbaseC,
                                    const int2* __restrict__ stagingC,
                                    const float* __restrict__ dinv,
                                    float* __restrict__ presum, int N) {
    __shared__ float bins[256];
    int t = threadIdx.x;
    int b = blockIdx.x;
    int base = bbaseC[b], end = bbaseC[b + 1];
    bins[t] = 0.f;
    __syncthreads();
    for (int e = base + t; e < end; e += 256) {
        int2 w = stagingC[e];
        int r = w.x & 0xFFFFFF;
        int cl = (w.x >> 24) & 255;
        float pre = -dinv[r] * __int_as_float(w.y);
        atomicAdd(&bins[cl], pre);   // LDS float atomic
    }
    __syncthreads();
    int grow = (b << 8) + t;
    if (grow < N) presum[grow] = bins[t];
}

// ---- h1 = leaky_relu(x @ w1 + b1) ---------------------------------------
// Outputs: h1b (bf16 pairs, 64B/row: word w = feats 2w,2w+1) for h2pool,
//          h1q (fp8 e4m3 * dinv, 32B/row) for the gather.
__global__ void h1_kernel(const float* __restrict__ x, const float* __restrict__ w,
                          const float* __restrict__ b, const float* __restrict__ dinv,
                          uint4* __restrict__ h1b, uint4* __restrict__ h1q, int N) {
    __shared__ float ws[20 * 32];
    __shared__ float bs[32];
    for (int t = threadIdx.x; t < 640; t += blockDim.x) ws[t] = w[t];
    if (threadIdx.x < 32) bs[threadIdx.x] = b[threadIdx.x];
    __syncthreads();
    int i = blockIdx.x * blockDim.x + threadIdx.x;
    if (i >= N) return;
    float xi[20];
#pragma unroll
    for (int k = 0; k < 20; k++) xi[k] = x[i * 20 + k];
    float acc[32];
#pragma unroll
    for (int j = 0; j < 32; j++) acc[j] = bs[j];
#pragma unroll
    for (int k = 0; k < 20; k++) {
        float a = xi[k];
#pragma unroll
        for (int j = 0; j < 32; j++) acc[j] += a * ws[k * 32 + j];
    }
#pragma unroll
    for (int j = 0; j < 32; j++) {
        float v = acc[j];
        acc[j] = v > 0.f ? v : v * NEG_SLOPE;
    }
    unsigned u[16];
#pragma unroll
    for (int k = 0; k < 16; k++) u[k] = pack2(acc[2 * k], acc[2 * k + 1]);
#pragma unroll
    for (int q = 0; q < 4; q++)
        h1b[(long)i * 4 + q] = make_uint4(u[4 * q], u[4 * q + 1], u[4 * q + 2], u[4 * q + 3]);
    float di = dinv[i];
    unsigned wds[8];
#pragma unroll
    for (int wq = 0; wq < 8; wq++) {
        unsigned wd = 0;
#pragma unroll
        for (int j = 0; j < 4; j++)
            wd |= (unsigned)e8(di * acc[wq * 4 + j]) << (8 * j);
        wds[wq] = wd;
    }
    h1q[(long)i * 2 + 0] = make_uint4(wds[0], wds[1], wds[2], wds[3]);
    h1q[(long)i * 2 + 1] = make_uint4(wds[4], wds[5], wds[6], wds[7]);
}

// ---- pure gather-propagate (no atomics), fp8 operand --------------------
// p1[i] = sum_{e in CSR row i} pre_e * h1q[col_e]   (dinv[col] baked into h1q)
// 4 threads per node, each owning 8 fp8 features (one uint2 = 32B/row total).
__global__ void gather_kernel(const int* __restrict__ rowptr, const int2* __restrict__ sorted,
                              const uint2* __restrict__ h1q, uint4* __restrict__ p1b, int N) {
    long idx = (long)blockIdx.x * blockDim.x + threadIdx.x;
    int node = (int)(idx >> 2);
    int part = (int)(idx & 3);
    if (node >= N) return;
    int s0 = rowptr[node], s1 = rowptr[node + 1];
    float acc[8];
#pragma unroll
    for (int k = 0; k < 8; k++) acc[k] = 0.f;
    int e = s0;
    for (; e + 4 <= s1; e += 4) {
        int2 q0 = sorted[e], q1 = sorted[e + 1], q2 = sorted[e + 2], q3 = sorted[e + 3];
        float n0 = __int_as_float(q0.y), n1 = __int_as_float(q1.y);
        float n2 = __int_as_float(q2.y), n3 = __int_as_float(q3.y);
        uint2 v0 = h1q[(long)q0.x * 4 + part];
        uint2 v1 = h1q[(long)q1.x * 4 + part];
        uint2 v2 = h1q[(long)q2.x * 4 + part];
        uint2 v3 = h1q[(long)q3.x * 4 + part];
#pragma unroll
        for (int j = 0; j < 4; j++) {
            acc[j]     += n0 * d8(v0.x, j) + n1 * d8(v1.x, j) + n2 * d8(v2.x, j) + n3 * d8(v3.x, j);
            acc[4 + j] += n0 * d8(v0.y, j) + n1 * d8(v1.y, j) + n2 * d8(v2.y, j) + n3 * d8(v3.y, j);
        }
    }
    for (; e < s1; e++) {
        int2 q = sorted[e];
        float nm = __int_as_float(q.y);
        uint2 v = h1q[(long)q.x * 4 + part];
#pragma unroll
        for (int j = 0; j < 4; j++) {
            acc[j]     += nm * d8(v.x, j);
            acc[4 + j] += nm * d8(v.y, j);
        }
    }
    // p1b keeps the bf16 pair layout: word w holds features (2w, 2w+1).
    p1b[(long)node * 4 + part] = make_uint4(pack2(acc[0], acc[1]), pack2(acc[2], acc[3]),
                                            pack2(acc[4], acc[5]), pack2(acc[6], acc[7]));
}

// ---- fused h2 + pooled sums, v3: feature-per-lane, bf16 h1 + p1 ---------
// Lane l owns output feature j=l. w0col/w1col (32 floats each) live in regs.
// h1 and p1 rows are both 16 packed-bf16 words; lanes 0-15 hold word m=lane,
// shfl broadcasts word k>>1 (features k, k+1) to all lanes.
__global__ void __launch_bounds__(256, 1)
h2pool_kernel(const uint4* __restrict__ h1b, const uint4* __restrict__ p1b,
              const float* __restrict__ presum, const float* __restrict__ dinv,
              const float* __restrict__ w0, const float* __restrict__ w1,
              const float* __restrict__ b, float* __restrict__ sbuf, int N, int W) {
    __shared__ float wred[4][128];
    int t = threadIdx.x;
    int lane = t & 63, wv = t >> 6;
    float w0r[32], w1r[32];
#pragma unroll
    for (int k = 0; k < 32; k++) {
        w0r[k] = w0[k * 64 + lane];   // column j=lane of w2_0 (32x64 row-major)
        w1r[k] = w1[k * 64 + lane];
    }
    float bj = b[lane];
    const unsigned* h1w = (const unsigned*)h1b;
    const unsigned* p1w = (const unsigned*)p1b;
    float s1 = 0.f, s2 = 0.f;
    int gw = blockIdx.x * 4 + wv;     // global wave id; W = total waves
    for (int i = gw; i < N; i += W) {
        unsigned hw = h1w[(long)i * 16 + (lane & 15)];  // lane m holds h1 word m
        unsigned pw = p1w[(long)i * 16 + (lane & 15)];  // lane m holds p1 word m
        float cwi = presum[i] * dinv[i];                // uniform -> broadcast
        float a0 = bj, a1 = 0.f, a2 = 0.f, a3 = 0.f;
#pragma unroll
        for (int k = 0; k < 32; k += 4) {
            unsigned hA = __shfl(hw, k >> 1);       // h1 features k, k+1
            unsigned hB = __shfl(hw, (k >> 1) + 1); // h1 features k+2, k+3
            unsigned pA = __shfl(pw, k >> 1);       // p1 features k, k+1
            unsigned pB = __shfl(pw, (k >> 1) + 1); // p1 features k+2, k+3
            a0 += blo(hA) * w0r[k]     + blo(pA) * w1r[k];
            a1 += bhi(hA) * w0r[k + 1] + bhi(pA) * w1r[k + 1];
            a2 += blo(hB) * w0r[k + 2] + blo(pB) * w1r[k + 2];
            a3 += bhi(hB) * w0r[k + 3] + bhi(pB) * w1r[k + 3];
        }
        float v = (a0 + a1) + (a2 + a3);
        v = v > 0.f ? v : v * NEG_SLOPE;
        s1 += v;
        s2 += cwi * v;
    }
    wred[wv][lane] = s1;
    wred[wv][64 + lane] = s2;
    __syncthreads();
    if (t < 128) {
        float s = wred[0][t] + wred[1][t] + wred[2][t] + wred[3][t];
        atomAddF(&sbuf[(blockIdx.x & (NREP - 1)) * 128 + t], s);
    }
}

// ---- pooled = (s1/N)@w30 + (s2/N)@w31 + b3; out = log_softmax -----------
__global__ void final_kernel(const float* __restrict__ sbuf,
                             const float* __restrict__ w30, const float* __restrict__ w31,
                             const float* __restrict__ b3, float* __restrict__ out, float invN) {
    __shared__ float s1s[64];
    __shared__ float s2s[64];
    int t = threadIdx.x;
    float s1 = 0.f, s2 = 0.f;
#pragma unroll
    for (int r = 0; r < NREP; r++) {
        s1 += sbuf[r * 128 + t];
        s2 += sbuf[r * 128 + 64 + t];
    }
    s1s[t] = s1;
    s2s[t] = s2;
    __syncthreads();
    if (t != 0) return;
    float p[2];
    for (int c = 0; c < 2; c++) {
        float a = 0.f;
        for (int k = 0; k < 64; k++) a += s1s[k] * w30[k * 2 + c] + s2s[k] * w31[k * 2 + c];
        p[c] = a * invN + b3[c];
    }
    float m = fmaxf(p[0], p[1]);
    float lse = m + logf(expf(p[0] - m) + expf(p[1] - m));
    out[0] = p[0] - lse;
    out[1] = p[1] - lse;
}

extern "C" void kernel_launch(void* const* d_in, const int* in_sizes, int n_in,
                              void* d_out, int out_size, void* d_ws, size_t ws_size,
                              hipStream_t stream) {
    const float* x    = (const float*)d_in[0];
    const int*   ei   = (const int*)d_in[1];
    const float* attr = (const float*)d_in[2];
    const float* w1_0 = (const float*)d_in[3];
    const float* b1   = (const float*)d_in[4];
    const float* w2_0 = (const float*)d_in[5];
    const float* w2_1 = (const float*)d_in[6];
    const float* b2   = (const float*)d_in[7];
    const float* w3_0 = (const float*)d_in[8];
    const float* w3_1 = (const float*)d_in[9];
    const float* b3   = (const float*)d_in[10];

    const int N = in_sizes[0] / 20;   // 100000
    const int E = in_sizes[2];        // 3200000
    const int* row = ei;
    const int* col = ei + E;
    const int NB = (N + 255) >> 8;    // 391 buckets (<= 512)

    // workspace layout (words)
    long big = (long)(2L * E > 64L * N ? 2L * E : 64L * N);
    float* ws = (float*)d_ws;
    float* dinv   = ws;                            // N
    float* presum = ws + N;                        // N
    int*   rowptr = (int*)(ws + 2L * N);           // N+1 (alloc N+4)
    long   off    = 3L * N + 4;
    int*   bhR    = (int*)(ws + off); off += 512L * PAD;   // row hist (padded)
    int*   bhC    = (int*)(ws + off); off += 512L * PAD;   // col hist (padded)
    int*   bbaseR = (int*)(ws + off); off += 516;
    int*   bbaseC = (int*)(ws + off); off += 516;
    int*   bcurR  = (int*)(ws + off); off += 512L * PAD;
    int*   bcurC  = (int*)(ws + off); off += 512L * PAD;
    float* sbuf   = ws + off;         off += NREP * 128;   // replicated pooled sums
    long   offA   = (off + 15) & ~15L;                     // 64B-align regA
    float* regA   = ws + offA;                  // big: stagingR -> sorted (in-place)
    float* regB   = regA + big;                 // big: stagingC -> h1b+p1b+h1q

    int2*  stagingR = (int2*)regA;              // rewritten in-place as sorted
    int2*  sorted   = (int2*)regA;              // == stagingR region; dead after gather
    int2*  stagingC = (int2*)regB;              // dead after col_finalize
    uint4* h1b      = (uint4*)regB;             // bf16 pairs, 16N words (over stagingC)
    uint4* p1b      = (uint4*)(regB + 16L * N); // bf16, 16N words
    uint4* h1q      = (uint4*)(regB + 32L * N); // fp8 (dinv-scaled), 8N words

    // zero accumulated regions (ws is poisoned before every launch)
    hipMemsetAsync(bhR, 0, 2 * 512 * PAD * 4, stream);   // bhR + bhC contiguous
    hipMemsetAsync(sbuf, 0, NREP * 128 * 4, stream);

    const int B = 256;
    const int NCH = (E + CH - 1) / CH;   // chunk-blocks for hist/scatter
    hist2_kernel<<<NCH, B, 0, stream>>>(row, col, bhR, bhC, E, NB);
    bucket_scan2_kernel<<<2, 512, 0, stream>>>(bhR, bhC, bbaseR, bbaseC, bcurR, bcurC,
                                               rowptr, NB, N, E);
    scatter2_kernel<<<NCH, B, 0, stream>>>(row, col, attr, bcurR, bcurC, stagingR, stagingC, E, NB);
    rowfin_kernel<<<NB, 256, 0, stream>>>(bbaseR, stagingR, sorted, rowptr, dinv, N);  // in-place
    col_finalize_kernel<<<NB, 256, 0, stream>>>(bbaseC, stagingC, dinv, presum, N);    // frees regB
    h1_kernel<<<(N + B - 1) / B, B, 0, stream>>>(x, w1_0, b1, dinv, h1b, h1q, N);
    {
        long t = (long)N * 4;
        gather_kernel<<<(int)((t + B - 1) / B), B, 0, stream>>>(rowptr, sorted, (const uint2*)h1q, p1b, N);
    }
    h2pool_kernel<<<H2B, B, 0, stream>>>(h1b, p1b, presum, dinv, w2_0, w2_1, b2, sbuf, N, H2B * 4);
    final_kernel<<<1, 64, 0, stream>>>(sbuf, w3_0, w3_1, b3, (float*)d_out, 1.0f / (float)N);
}

// Round 15
// 400.429 us; speedup vs baseline: 1.4292x; 1.0094x over previous
//
#include <hip/hip_runtime.h>
#include <hip/hip_bf16.h>
#include <hip/hip_fp8.h>

#define NEG_SLOPE 0.01f
#define CH 4096            // edges per block in hist/scatter (LDS-aggregated)
#define PAD 16             // 64B stride for contended global counters
// Dual bucket sort: row-bucketed CSR for the gather, col-bucketed staging for
// the presum (cw) aggregation -> NO per-edge global atomics anywhere.
// bucket id = id >> 8 (256 ids per bucket); NB = ceil(N/256) <= 512.
// Packing: {other_id (<2^24) | low8(key_id) << 24}.
// scatter2: in-block LDS counting sort so staging writes stream out as
// contiguous runs per bucket (evidence R3->R4: fixed 4x write amplification).
// R11 LESSON (do not retry): CH=12288/SB=512 regressed. scatter2 ~97us PARKED
// (pattern-bound; occupancy-insensitive; CH=4096 is the 3-block/CU optimum).
// rowfin: fused rowdeg+rowsort, IN-PLACE (sorted overlays stagingR): whole
// bucket staged in LDS ebuf, all reads complete before any write.
// R15: ebuf entries packed to 4B -- pre = -dinv*attr is ALWAYS <= 0, so the
// sign bit is constant: entry = col(17b) | bf16-magnitude(15b). ebuf 72->36KB,
// rowfin LDS 110->72KB => 2 blocks/CU (was 1; rowfin was the hidden ~100+us
// latency-bound kernel: 4 waves/CU on LDS-atomic chains).
// NOTE: sorted itself STAYS int2 -- a 4B sorted overlaying 8B staging entries
// shifts the word mapping so block b would clobber bucket b/2's unread
// staging (cross-block WAR race). Do not shrink sorted in-place.
// Bucket size ~ Binomial(3.2M, 256/1e5): mean 8192, sigma 90; CAP=9216=+11sig.
// ORDERING: rowfin -> col_finalize (stagingC+dinv) -> h1 (regB over stagingC)
//           -> gather (sorted regA, h1q regB) -> h2pool.
// h1q is FP8 e4m3 (row 32B): gather footprint 3.2MB, L2-resident (R13: -13us).
// h1 kept ONLY as bf16 pairs (h2pool's sole stream); p1b bf16; accum fp32.
// h2pool v2 (feature-per-lane): weight columns in VGPRs, pooled sums in regs.
// R8 LESSON (do not retry): block-per-bucket LDS-accumulating GATHER collapsed
// parallelism -> 679us. Random-gather needs ~400K independent threads.
#define NT 32              // col tiles (col < 2^17 -> tile = col>>12 in [0,32))
#define TILE_SHIFT 12      // tile-sorted rows keep the gather window compact
#define KEYS (256 * NT)    // row-sort bins: (rowlow, tile)
#define CAP 9216           // rowfin LDS staging capacity (entries per bucket)
#define H2B 512            // h2pool grid (2048 waves, grid-stride over nodes)
#define NREP 16            // sbuf replicas (atomic contention divider)

__device__ __forceinline__ void atomAddF(float* p, float v) {
    unsafeAtomicAdd(p, v);
}

// bf16 pack/unpack (round-to-nearest-even; finite values only)
__device__ __forceinline__ unsigned bf16rn(float f) {
    unsigned u = __float_as_uint(f);
    return (u + 0x7FFFu + ((u >> 16) & 1u)) >> 16;
}
__device__ __forceinline__ unsigned pack2(float a, float b) {
    return bf16rn(a) | (bf16rn(b) << 16);
}
__device__ __forceinline__ float blo(unsigned u) { return __uint_as_float(u << 16); }
__device__ __forceinline__ float bhi(unsigned u) { return __uint_as_float(u & 0xFFFF0000u); }

// fp8 e4m3 (OCP) encode/decode via HIP type
__device__ __forceinline__ unsigned char e8(float f) {
    __hip_fp8_e4m3 q(f);
    return (unsigned char)q.__x;
}
__device__ __forceinline__ float d8(unsigned w, int b) {
    __hip_fp8_e4m3 q;
    q.__x = (__hip_fp8_storage_t)((w >> (b * 8)) & 0xFF);
    return (float)q;
}

// wave-inclusive scan of v (64 lanes)
__device__ __forceinline__ int waveInclScan(int v, int lane) {
#pragma unroll
    for (int off = 1; off < 64; off <<= 1) {
        int u = __shfl_up(v, off);
        if (lane >= off) v += u;
    }
    return v;
}

// ---- phase 1: dual bucket histogram (row and col), block-aggregated -----
__global__ void hist2_kernel(const int* __restrict__ row, const int* __restrict__ col,
                             int* __restrict__ bhR, int* __restrict__ bhC, int E, int NB) {
    __shared__ int lhR[512];
    __shared__ int lhC[512];
    for (int t = threadIdx.x; t < 512; t += 256) { lhR[t] = 0; lhC[t] = 0; }
    __syncthreads();
    int base = blockIdx.x * CH;
    int end = min(base + CH, E);
    for (int e = base + threadIdx.x; e < end; e += 256) {
        atomicAdd(&lhR[row[e] >> 8], 1);
        atomicAdd(&lhC[col[e] >> 8], 1);
    }
    __syncthreads();
    for (int t = threadIdx.x; t < NB; t += 256) {
        if (lhR[t]) atomicAdd(&bhR[t * PAD], lhR[t]);
        if (lhC[t]) atomicAdd(&bhC[t * PAD], lhC[t]);
    }
}

// ---- phase 2: exclusive scans of both bucket-count arrays (one launch) --
// block 0: R side (+ rowptr[N] = E); block 1: C side.
__global__ void bucket_scan2_kernel(const int* __restrict__ bhR, const int* __restrict__ bhC,
                                    int* __restrict__ bbaseR, int* __restrict__ bbaseC,
                                    int* __restrict__ bcurR, int* __restrict__ bcurC,
                                    int* __restrict__ rowptr, int NB, int N, int E) {
    const int* bh = blockIdx.x ? bhC : bhR;
    int* bbase    = blockIdx.x ? bbaseC : bbaseR;
    int* bcur     = blockIdx.x ? bcurC : bcurR;
    __shared__ int s[512];
    int t = threadIdx.x;
    int v = (t < NB) ? bh[t * PAD] : 0;
    s[t] = v;
    __syncthreads();
    for (int off = 1; off < 512; off <<= 1) {
        int x = (t >= off) ? s[t - off] : 0;
        __syncthreads();
        s[t] += x;
        __syncthreads();
    }
    if (t < NB) { bbase[t] = s[t] - v; bcur[t * PAD] = s[t] - v; }
    if (t == 0) {
        bbase[NB] = E;
        if (blockIdx.x == 0) rowptr[N] = E;
    }
}

// ---- phase 3: dual scatter with in-block LDS counting sort --------------
// stagingR (row-bucketed): {col | rowlow<<24, attr}
// stagingC (col-bucketed): {row | collow<<24, attr}
__global__ void __launch_bounds__(256, 1)
scatter2_kernel(const int* __restrict__ row, const int* __restrict__ col,
                const float* __restrict__ attr,
                int* __restrict__ bcurR, int* __restrict__ bcurC,
                int2* __restrict__ stagingR, int2* __restrict__ stagingC,
                int E, int NB) {
    __shared__ int lh[512];
    __shared__ int lbase[512];
    __shared__ int loff[512];
    __shared__ int lcur[512];
    __shared__ int wsum[4];
    __shared__ int2 buf[CH];              // 32KB: block's edges grouped by bucket
    __shared__ unsigned short bkid[CH];   // 8KB: bucket id per entry
    int t = threadIdx.x;
    int lane = t & 63, wv = t >> 6;
    int base = blockIdx.x * CH;
    int end = min(base + CH, E);
    int cnt = end - base;

    for (int side = 0; side < 2; side++) {
        const int* key   = side ? col : row;
        const int* other = side ? row : col;
        int* bcur        = side ? bcurC : bcurR;
        int2* out        = side ? stagingC : stagingR;
        // hist
        for (int k = t; k < 512; k += 256) { lh[k] = 0; lcur[k] = 0; }
        __syncthreads();
        for (int e = base + t; e < end; e += 256)
            atomicAdd(&lh[key[e] >> 8], 1);
        __syncthreads();
        // reserve global runs
        for (int k = t; k < NB; k += 256)
            if (lh[k]) lbase[k] = atomicAdd(&bcur[k * PAD], lh[k]);
        // local exclusive scan of lh[0..511]: pair per thread, shfl wave scan
        int a0 = lh[2 * t], a1 = lh[2 * t + 1];
        int psum = a0 + a1;
        int incl = waveInclScan(psum, lane);
        if (lane == 63) wsum[wv] = incl;
        __syncthreads();
        int wadd = 0;
        for (int w = 0; w < wv; w++) wadd += wsum[w];
        int pexcl = incl + wadd - psum;
        loff[2 * t] = pexcl;
        loff[2 * t + 1] = pexcl + a0;
        __syncthreads();
        // place into LDS grouped by bucket
        for (int e = base + t; e < end; e += 256) {
            int k = key[e], o = other[e];
            int bk = k >> 8;
            int rank = atomicAdd(&lcur[bk], 1);
            int lpos = loff[bk] + rank;
            buf[lpos] = make_int2(o | ((k & 255) << 24), __float_as_int(attr[e]));
            bkid[lpos] = (unsigned short)bk;
        }
        __syncthreads();
        // coalesced write-out: consecutive j -> consecutive dst within runs
        for (int j = t; j < cnt; j += 256) {
            int bk = bkid[j];
            out[lbase[bk] + (j - loff[bk])] = buf[j];
        }
        __syncthreads();
    }
}

// ---- phase 4a: fused degree + counting sort, IN-PLACE -------------------
// Block b owns bucket b = rows [b*256, b*256+256) exclusively.
// ebuf entry: col(17b) | bf16rn(dinv*attr)(15b, sign implicit negative).
__global__ void __launch_bounds__(256, 1)
rowfin_kernel(const int* __restrict__ bbaseR, const int2* __restrict__ stagingR,
              int2* __restrict__ sorted /*aliases stagingR*/,
              int* __restrict__ rowptr, float* __restrict__ dinv, int N) {
    __shared__ int lcount[KEYS];      // 32KB: counts -> cursors
    __shared__ unsigned ebuf[CAP];    // 36KB: packed sorted bucket staging
    __shared__ float ldeg[256];
    __shared__ float sdinv[256];
    __shared__ int wsum[4];
    int t = threadIdx.x;
    int lane = t & 63, wv = t >> 6;
    int b = blockIdx.x;
    int base = bbaseR[b], end = bbaseR[b + 1];
    int cnt = end - base;
    for (int k = t; k < KEYS; k += 256) lcount[k] = 0;
    ldeg[t] = 0.f;
    __syncthreads();
    // pass1: histogram + degree
    for (int e = base + t; e < end; e += 256) {
        int2 w = stagingR[e];
        int rl = (w.x >> 24) & 255;
        int tile = (w.x & 0xFFFFFF) >> TILE_SHIFT;
        atomicAdd(&lcount[rl * NT + tile], 1);
        atomicAdd(&ldeg[rl], __int_as_float(w.y));
    }
    __syncthreads();
    // per-row serial scan of NT bins; s = row total
    int vals[NT];
    int s = 0;
#pragma unroll
    for (int j = 0; j < NT; j++) { vals[j] = s; s += lcount[t * NT + j]; }
    int incl = waveInclScan(s, lane);
    if (lane == 63) wsum[wv] = incl;
    __syncthreads();
    int wadd = 0;
    for (int w = 0; w < wv; w++) wadd += wsum[w];
    int rowexcl = incl + wadd - s;
#pragma unroll
    for (int j = 0; j < NT; j++) lcount[t * NT + j] = rowexcl + vals[j];  // -> cursors
    int grow = (b << 8) + t;
    float d = ldeg[t];
    float di = d > 0.f ? rsqrtf(d) : 0.f;
    sdinv[t] = di;
    if (grow < N) {
        rowptr[grow] = base + rowexcl;
        dinv[grow] = di;
    }
    __syncthreads();
    // pass2: place packed {col|mag15<<17} into LDS at sorted pos (reads L2-hot)
    for (int e = base + t; e < end; e += 256) {
        int2 w = stagingR[e];
        int rl = (w.x >> 24) & 255;
        int c = w.x & 0xFFFFFF;
        int key = rl * NT + (c >> TILE_SHIFT);
        int pos = atomicAdd(&lcount[key], 1);
        float mag = sdinv[rl] * __int_as_float(w.y);   // >= 0
        unsigned pk = (unsigned)c | (bf16rn(mag) << 17);
        if (pos < CAP) ebuf[pos] = pk;
        else {  // statistically impossible (>mean+11sigma)
            unsigned m16 = (pk >> 17) << 16;
            sorted[base + pos] = make_int2(c, (int)(m16 | 0x80000000u));
        }
    }
    __syncthreads();
    // pass3: unpack + linear stream-out over the block's own (fully-read) range
    int lim = min(cnt, CAP);
    for (int j = t; j < lim; j += 256) {
        unsigned pk = ebuf[j];
        unsigned m16 = (pk >> 17) << 16;                   // bf16 magnitude bits
        sorted[base + j] = make_int2((int)(pk & 0x1FFFFu), (int)(m16 | 0x80000000u));
    }
}

// ---- phase 4b: per-col-bucket presum (NO global atomics) ----------------
// presum[c] = sum_{e: col=c} -dinv[row_e] * attr_e
// Runs after rowfin (needs dinv); MUST run before h1 (h1 overlays stagingC).
__global__ void col_finalize_kernel(const int* __restrict__ bbaseC,
                                    const int2* __restrict__ stagingC,
                                    const float* __restrict__ dinv,
                                    float* __restrict__ presum, int N) {
    __shared__ float bins[256];
    int t = threadIdx.x;
    int b = blockIdx.x;
    int base = bbaseC[b], end = bbaseC[b + 1];
    bins[t] = 0.f;
    __syncthreads();
    for (int e = base + t; e < end; e += 256) {
        int2 w = stagingC[e];
        int r = w.x & 0xFFFFFF;
        int cl = (w.x >> 24) & 255;
        float pre = -dinv[r] * __int_as_float(w.y);
        atomicAdd(&bins[cl], pre);   // LDS float atomic
    }
    __syncthreads();
    int grow = (b << 8) + t;
    if (grow < N) presum[grow] = bins[t];
}

// ---- h1 = leaky_relu(x @ w1 + b1) ---------------------------------------
// Outputs: h1b (bf16 pairs, 64B/row: word w = feats 2w,2w+1) for h2pool,
//          h1q (fp8 e4m3 * dinv, 32B/row) for the gather.
__global__ void h1_kernel(const float* __restrict__ x, const float* __restrict__ w,
                          const float* __restrict__ b, const float* __restrict__ dinv,
                          uint4* __restrict__ h1b, uint4* __restrict__ h1q, int N) {
    __shared__ float ws[20 * 32];
    __shared__ float bs[32];
    for (int t = threadIdx.x; t < 640; t += blockDim.x) ws[t] = w[t];
    if (threadIdx.x < 32) bs[threadIdx.x] = b[threadIdx.x];
    __syncthreads();
    int i = blockIdx.x * blockDim.x + threadIdx.x;
    if (i >= N) return;
    float xi[20];
#pragma unroll
    for (int k = 0; k < 20; k++) xi[k] = x[i * 20 + k];
    float acc[32];
#pragma unroll
    for (int j = 0; j < 32; j++) acc[j] = bs[j];
#pragma unroll
    for (int k = 0; k < 20; k++) {
        float a = xi[k];
#pragma unroll
        for (int j = 0; j < 32; j++) acc[j] += a * ws[k * 32 + j];
    }
#pragma unroll
    for (int j = 0; j < 32; j++) {
        float v = acc[j];
        acc[j] = v > 0.f ? v : v * NEG_SLOPE;
    }
    unsigned u[16];
#pragma unroll
    for (int k = 0; k < 16; k++) u[k] = pack2(acc[2 * k], acc[2 * k + 1]);
#pragma unroll
    for (int q = 0; q < 4; q++)
        h1b[(long)i * 4 + q] = make_uint4(u[4 * q], u[4 * q + 1], u[4 * q + 2], u[4 * q + 3]);
    float di = dinv[i];
    unsigned wds[8];
#pragma unroll
    for (int wq = 0; wq < 8; wq++) {
        unsigned wd = 0;
#pragma unroll
        for (int j = 0; j < 4; j++)
            wd |= (unsigned)e8(di * acc[wq * 4 + j]) << (8 * j);
        wds[wq] = wd;
    }
    h1q[(long)i * 2 + 0] = make_uint4(wds[0], wds[1], wds[2], wds[3]);
    h1q[(long)i * 2 + 1] = make_uint4(wds[4], wds[5], wds[6], wds[7]);
}

// ---- pure gather-propagate (no atomics), fp8 operand --------------------
// p1[i] = sum_{e in CSR row i} pre_e * h1q[col_e]   (dinv[col] baked into h1q)
// 4 threads per node, each owning 8 fp8 features (one uint2 = 32B/row total).
__global__ void gather_kernel(const int* __restrict__ rowptr, const int2* __restrict__ sorted,
                              const uint2* __restrict__ h1q, uint4* __restrict__ p1b, int N) {
    long idx = (long)blockIdx.x * blockDim.x + threadIdx.x;
    int node = (int)(idx >> 2);
    int part = (int)(idx & 3);
    if (node >= N) return;
    int s0 = rowptr[node], s1 = rowptr[node + 1];
    float acc[8];
#pragma unroll
    for (int k = 0; k < 8; k++) acc[k] = 0.f;
    int e = s0;
    for (; e + 4 <= s1; e += 4) {
        int2 q0 = sorted[e], q1 = sorted[e + 1], q2 = sorted[e + 2], q3 = sorted[e + 3];
        float n0 = __int_as_float(q0.y), n1 = __int_as_float(q1.y);
        float n2 = __int_as_float(q2.y), n3 = __int_as_float(q3.y);
        uint2 v0 = h1q[(long)q0.x * 4 + part];
        uint2 v1 = h1q[(long)q1.x * 4 + part];
        uint2 v2 = h1q[(long)q2.x * 4 + part];
        uint2 v3 = h1q[(long)q3.x * 4 + part];
#pragma unroll
        for (int j = 0; j < 4; j++) {
            acc[j]     += n0 * d8(v0.x, j) + n1 * d8(v1.x, j) + n2 * d8(v2.x, j) + n3 * d8(v3.x, j);
            acc[4 + j] += n0 * d8(v0.y, j) + n1 * d8(v1.y, j) + n2 * d8(v2.y, j) + n3 * d8(v3.y, j);
        }
    }
    for (; e < s1; e++) {
        int2 q = sorted[e];
        float nm = __int_as_float(q.y);
        uint2 v = h1q[(long)q.x * 4 + part];
#pragma unroll
        for (int j = 0; j < 4; j++) {
            acc[j]     += nm * d8(v.x, j);
            acc[4 + j] += nm * d8(v.y, j);
        }
    }
    // p1b keeps the bf16 pair layout: word w holds features (2w, 2w+1).
    p1b[(long)node * 4 + part] = make_uint4(pack2(acc[0], acc[1]), pack2(acc[2], acc[3]),
                                            pack2(acc[4], acc[5]), pack2(acc[6], acc[7]));
}

// ---- fused h2 + pooled sums, v3: feature-per-lane, bf16 h1 + p1 ---------
// Lane l owns output feature j=l. w0col/w1col (32 floats each) live in regs.
// h1 and p1 rows are both 16 packed-bf16 words; lanes 0-15 hold word m=lane,
// shfl broadcasts word k>>1 (features k, k+1) to all lanes.
__global__ void __launch_bounds__(256, 1)
h2pool_kernel(const uint4* __restrict__ h1b, const uint4* __restrict__ p1b,
              const float* __restrict__ presum, const float* __restrict__ dinv,
              const float* __restrict__ w0, const float* __restrict__ w1,
              const float* __restrict__ b, float* __restrict__ sbuf, int N, int W) {
    __shared__ float wred[4][128];
    int t = threadIdx.x;
    int lane = t & 63, wv = t >> 6;
    float w0r[32], w1r[32];
#pragma unroll
    for (int k = 0; k < 32; k++) {
        w0r[k] = w0[k * 64 + lane];   // column j=lane of w2_0 (32x64 row-major)
        w1r[k] = w1[k * 64 + lane];
    }
    float bj = b[lane];
    const unsigned* h1w = (const unsigned*)h1b;
    const unsigned* p1w = (const unsigned*)p1b;
    float s1 = 0.f, s2 = 0.f;
    int gw = blockIdx.x * 4 + wv;     // global wave id; W = total waves
    for (int i = gw; i < N; i += W) {
        unsigned hw = h1w[(long)i * 16 + (lane & 15)];  // lane m holds h1 word m
        unsigned pw = p1w[(long)i * 16 + (lane & 15)];  // lane m holds p1 word m
        float cwi = presum[i] * dinv[i];                // uniform -> broadcast
        float a0 = bj, a1 = 0.f, a2 = 0.f, a3 = 0.f;
#pragma unroll
        for (int k = 0; k < 32; k += 4) {
            unsigned hA = __shfl(hw, k >> 1);       // h1 features k, k+1
            unsigned hB = __shfl(hw, (k >> 1) + 1); // h1 features k+2, k+3
            unsigned pA = __shfl(pw, k >> 1);       // p1 features k, k+1
            unsigned pB = __shfl(pw, (k >> 1) + 1); // p1 features k+2, k+3
            a0 += blo(hA) * w0r[k]     + blo(pA) * w1r[k];
            a1 += bhi(hA) * w0r[k + 1] + bhi(pA) * w1r[k + 1];
            a2 += blo(hB) * w0r[k + 2] + blo(pB) * w1r[k + 2];
            a3 += bhi(hB) * w0r[k + 3] + bhi(pB) * w1r[k + 3];
        }
        float v = (a0 + a1) + (a2 + a3);
        v = v > 0.f ? v : v * NEG_SLOPE;
        s1 += v;
        s2 += cwi * v;
    }
    wred[wv][lane] = s1;
    wred[wv][64 + lane] = s2;
    __syncthreads();
    if (t < 128) {
        float s = wred[0][t] + wred[1][t] + wred[2][t] + wred[3][t];
        atomAddF(&sbuf[(blockIdx.x & (NREP - 1)) * 128 + t], s);
    }
}

// ---- pooled = (s1/N)@w30 + (s2/N)@w31 + b3; out = log_softmax -----------
__global__ void final_kernel(const float* __restrict__ sbuf,
                             const float* __restrict__ w30, const float* __restrict__ w31,
                             const float* __restrict__ b3, float* __restrict__ out, float invN) {
    __shared__ float s1s[64];
    __shared__ float s2s[64];
    int t = threadIdx.x;
    float s1 = 0.f, s2 = 0.f;
#pragma unroll
    for (int r = 0; r < NREP; r++) {
        s1 += sbuf[r * 128 + t];
        s2 += sbuf[r * 128 + 64 + t];
    }
    s1s[t] = s1;
    s2s[t] = s2;
    __syncthreads();
    if (t != 0) return;
    float p[2];
    for (int c = 0; c < 2; c++) {
        float a = 0.f;
        for (int k = 0; k < 64; k++) a += s1s[k] * w30[k * 2 + c] + s2s[k] * w31[k * 2 + c];
        p[c] = a * invN + b3[c];
    }
    float m = fmaxf(p[0], p[1]);
    float lse = m + logf(expf(p[0] - m) + expf(p[1] - m));
    out[0] = p[0] - lse;
    out[1] = p[1] - lse;
}

extern "C" void kernel_launch(void* const* d_in, const int* in_sizes, int n_in,
                              void* d_out, int out_size, void* d_ws, size_t ws_size,
                              hipStream_t stream) {
    const float* x    = (const float*)d_in[0];
    const int*   ei   = (const int*)d_in[1];
    const float* attr = (const float*)d_in[2];
    const float* w1_0 = (const float*)d_in[3];
    const float* b1   = (const float*)d_in[4];
    const float* w2_0 = (const float*)d_in[5];
    const float* w2_1 = (const float*)d_in[6];
    const float* b2   = (const float*)d_in[7];
    const float* w3_0 = (const float*)d_in[8];
    const float* w3_1 = (const float*)d_in[9];
    const float* b3   = (const float*)d_in[10];

    const int N = in_sizes[0] / 20;   // 100000
    const int E = in_sizes[2];        // 3200000
    const int* row = ei;
    const int* col = ei + E;
    const int NB = (N + 255) >> 8;    // 391 buckets (<= 512)

    // workspace layout (words)
    long big = (long)(2L * E > 64L * N ? 2L * E : 64L * N);
    float* ws = (float*)d_ws;
    float* dinv   = ws;                            // N
    float* presum = ws + N;                        // N
    int*   rowptr = (int*)(ws + 2L * N);           // N+1 (alloc N+4)
    long   off    = 3L * N + 4;
    int*   bhR    = (int*)(ws + off); off += 512L * PAD;   // row hist (padded)
    int*   bhC    = (int*)(ws + off); off += 512L * PAD;   // col hist (padded)
    int*   bbaseR = (int*)(ws + off); off += 516;
    int*   bbaseC = (int*)(ws + off); off += 516;
    int*   bcurR  = (int*)(ws + off); off += 512L * PAD;
    int*   bcurC  = (int*)(ws + off); off += 512L * PAD;
    float* sbuf   = ws + off;         off += NREP * 128;   // replicated pooled sums
    long   offA   = (off + 15) & ~15L;                     // 64B-align regA
    float* regA   = ws + offA;                  // big: stagingR -> sorted (in-place)
    float* regB   = regA + big;                 // big: stagingC -> h1b+p1b+h1q

    int2*  stagingR = (int2*)regA;              // rewritten in-place as sorted
    int2*  sorted   = (int2*)regA;              // == stagingR region; dead after gather
    int2*  stagingC = (int2*)regB;              // dead after col_finalize
    uint4* h1b      = (uint4*)regB;             // bf16 pairs, 16N words (over stagingC)
    uint4* p1b      = (uint4*)(regB + 16L * N); // bf16, 16N words
    uint4* h1q      = (uint4*)(regB + 32L * N); // fp8 (dinv-scaled), 8N words

    // zero accumulated regions (ws is poisoned before every launch)
    hipMemsetAsync(bhR, 0, 2 * 512 * PAD * 4, stream);   // bhR + bhC contiguous
    hipMemsetAsync(sbuf, 0, NREP * 128 * 4, stream);

    const int B = 256;
    const int NCH = (E + CH - 1) / CH;   // chunk-blocks for hist/scatter
    hist2_kernel<<<NCH, B, 0, stream>>>(row, col, bhR, bhC, E, NB);
    bucket_scan2_kernel<<<2, 512, 0, stream>>>(bhR, bhC, bbaseR, bbaseC, bcurR, bcurC,
                                               rowptr, NB, N, E);
    scatter2_kernel<<<NCH, B, 0, stream>>>(row, col, attr, bcurR, bcurC, stagingR, stagingC, E, NB);
    rowfin_kernel<<<NB, 256, 0, stream>>>(bbaseR, stagingR, sorted, rowptr, dinv, N);  // in-place
    col_finalize_kernel<<<NB, 256, 0, stream>>>(bbaseC, stagingC, dinv, presum, N);    // frees regB
    h1_kernel<<<(N + B - 1) / B, B, 0, stream>>>(x, w1_0, b1, dinv, h1b, h1q, N);
    {
        long t = (long)N * 4;
        gather_kernel<<<(int)((t + B - 1) / B), B, 0, stream>>>(rowptr, sorted, (const uint2*)h1q, p1b, N);
    }
    h2pool_kernel<<<H2B, B, 0, stream>>>(h1b, p1b, presum, dinv, w2_0, w2_1, b2, sbuf, N, H2B * 4);
    final_kernel<<<1, 64, 0, stream>>>(sbuf, w3_0, w3_1, b3, (float*)d_out, 1.0f / (float)N);
}